// Round 6
// baseline (424.984 us; speedup 1.0000x reference)
//
#include <hip/hip_runtime.h>
#include <hip/hip_bf16.h>

namespace {

constexpr int C = 128, N = 256, T = 64, Bsz = 8;
constexpr int TILE = T * C;                       // 8192 elements per (b,n) slab
constexpr size_t BIGE = (size_t)Bsz * N * T * C;  // 16,777,216 elements

typedef short v8s __attribute__((ext_vector_type(8)));
typedef float v4f __attribute__((ext_vector_type(4)));

__device__ __forceinline__ float bfu(unsigned short u) {
  unsigned int x = ((unsigned int)u) << 16;
  return __uint_as_float(x);
}
__device__ __forceinline__ unsigned short f2b(float v) {
  __hip_bfloat16 h = __float2bfloat16(v);
  return *(unsigned short*)&h;
}
__device__ __forceinline__ unsigned int pk2(float a, float b) {
  return (unsigned int)f2b(a) | ((unsigned int)f2b(b) << 16);
}
// flag-aware load: f32 != 0 -> input is fp32, else bf16
__device__ __forceinline__ float ld(const void* p, size_t i, int f32) {
  if (f32) return ((const float*)p)[i];
  return bfu(((const unsigned short*)p)[i]);
}
__device__ __forceinline__ float sigm(float x) { return 1.f / (1.f + __expf(-x)); }

// ---------------------------------------------------------------- dtype sniffer
__global__ __launch_bounds__(64) void k_sniff(const unsigned short* x, int* flag) {
  __shared__ int cnt[64];
  int tid = threadIdx.x;
  int c = 0;
  for (int u = 0; u < 8; ++u) {
    unsigned short v = x[tid * 8 + u];
    int e = (v >> 7) & 255;
    c += (e >= 97 && e <= 157) ? 1 : 0;
  }
  cnt[tid] = c;
  __syncthreads();
  if (tid == 0) {
    int s = 0;
    for (int i = 0; i < 64; ++i) s += cnt[i];
    flag[0] = (s < 435) ? 1 : 0;  // <85% plausible-bf16 words -> fp32 input
  }
}

// ---------------------------------------------------------------- prep-all: weights + lap + emb in one launch
struct PrepArgs {
  const int* flag;
  const void *wq, *wk, *w1, *w2, *th, *dxc, *dec, *dc1;
  const void *bq, *bk, *b1, *b2, *l0g, *l0b, *l1g, *l1b, *dxcb, *decb, *dc1b, *dp2w, *dp2b;
  unsigned short *wqkB, *w1B, *w2B;        // bf16 [o][k]
  __hip_bfloat16* thB;                     // bf16 [o][k] (row-major, same as source)
  unsigned short *decWb, *dxcWb, *dc1Wb;   // bf16 [o][k], k = j*128+i
  float *bqk, *b1f, *b2f, *l0gf, *l0bf, *l1gf, *l1bf, *dxcbf, *decbf, *dc1bf, *dp2wf, *dp2bf;
};

// grid 200: blocks 0-127 weights, 128-191 lap (4 rows each), 192-199 emb (1 batch each)
__global__ __launch_bounds__(256) void k_prepall(
    PrepArgs a, const void* adj, float* lap, const int* step,
    const void* p1w, const void* p1b, const void* p2w, const void* p2b, float* e) {
  __shared__ float sh[256];
  __shared__ float e1[128];
  int f = a.flag[0];
  int blk = blockIdx.x, tid = threadIdx.x;
  if (blk < 128) {
    int idx = blk * 256 + tid;
    const int stride = 32768;
    // wqkB[o][k=j*128+ii], o<128 -> wq else wk. src w[(o*128+ii)*3 + j]
    for (int i = idx; i < 256 * 384; i += stride) {
      int o = i / 384, k = i - o * 384;
      int j = k >> 7, ii = k & 127;
      float v = (o < 128) ? ld(a.wq, (o * 128 + ii) * 3 + j, f)
                          : ld(a.wk, ((o - 128) * 128 + ii) * 3 + j, f);
      a.wqkB[i] = f2b(v);
    }
    for (int i = idx; i < 16384; i += stride) {
      a.w1B[i] = f2b(ld(a.w1, i, f));   // already [o][k] row-major
      a.w2B[i] = f2b(ld(a.w2, i, f));
      a.thB[i] = __float2bfloat16(ld(a.th, i, f));  // [o][k] row-major
    }
    // decoder conv weights -> bf16 [o][k = j*128 + ii]
    for (int i = idx; i < 16384; i += stride) {
      int o = i >> 7, ii = i & 127;
      int sbase = (o * 128 + ii) * 3;
#pragma unroll
      for (int j = 0; j < 3; ++j) {
        int dsti = o * 384 + j * 128 + ii;
        a.decWb[dsti] = f2b(ld(a.dec, sbase + j, f));
        a.dxcWb[dsti] = f2b(ld(a.dxc, sbase + j, f));
        a.dc1Wb[dsti] = f2b(ld(a.dc1, sbase + j, f));
      }
    }
    for (int i = idx; i < 256; i += stride) {
      a.bqk[i] = (i < 128) ? ld(a.bq, i, f) : ld(a.bk, i - 128, f);
      a.dp2wf[i] = ld(a.dp2w, i, f);
    }
    for (int i = idx; i < 128; i += stride) {
      a.b1f[i] = ld(a.b1, i, f);   a.b2f[i] = ld(a.b2, i, f);
      a.l0gf[i] = ld(a.l0g, i, f); a.l0bf[i] = ld(a.l0b, i, f);
      a.l1gf[i] = ld(a.l1g, i, f); a.l1bf[i] = ld(a.l1b, i, f);
      a.dxcbf[i] = ld(a.dxcb, i, f); a.decbf[i] = ld(a.decb, i, f); a.dc1bf[i] = ld(a.dc1b, i, f);
    }
    if (idx < 2) a.dp2bf[idx] = ld(a.dp2b, idx, f);
  } else if (blk < 192) {
    // lap: every block computes dsh (adj is L2-hot), writes its 4 rows
    float s = 0.f;
    for (int m = 0; m < 256; ++m) s += ld(adj, tid * 256 + m, f);
    sh[tid] = 1.f / sqrtf(s);
    __syncthreads();
    int n0 = (blk - 128) * 4;
    for (int idx = tid; idx < 1024; idx += 256) {
      int n = n0 + (idx >> 8), m = idx & 255;
      lap[n * 256 + m] = ld(adj, n * 256 + m, f) * sh[n] * sh[m];
    }
  } else {
    int b = blk - 192;
    if (tid < 128) {
      float sv = (float)step[b];
      int i0 = tid & 63;
      float fr = powf(10.f, (float)i0 / 63.f * 4.f);
      float ang = sv * fr;
      sh[tid] = (tid < 64) ? sinf(ang) : cosf(ang);
    }
    __syncthreads();
    if (tid < 128) {
      float aa = ld(p1b, tid, f);
      for (int i = 0; i < 128; ++i) aa += sh[i] * ld(p1w, tid * 128 + i, f);
      aa = aa * sigm(aa);
      e1[tid] = aa;
    }
    __syncthreads();
    if (tid < 128) {
      float a2 = ld(p2b, tid, f);
      for (int i = 0; i < 128; ++i) a2 += e1[i] * ld(p2w, tid * 128 + i, f);
      e[b * 128 + tid] = a2 * sigm(a2);
    }
  }
}

// ================================================================ mega1 v7 — hi/lo bf16 output.
constexpr int XBS = 136;  // Xb row stride (u16), 272B
constexpr int VTS = 72;   // vT row stride (u16), 144B

__global__ __launch_bounds__(512, 4) void k_mega1(
    const void* xin, const int* flag,
    const unsigned short* wqkB, const float* bqk,
    const unsigned short* w1B, const float* b1f,
    const unsigned short* w2B, const float* b2f,
    const float* l0g, const float* l0b,
    unsigned short* g0h, unsigned short* g0l) {
  int bn = blockIdx.x, b = bn >> 8, n = bn & 255;
  __shared__ unsigned short Xb[66 * XBS];    // x bf16, row t+1 = x[t]; rows 0,65 zero
  __shared__ unsigned short qo[64 * XBS];    // q bf16; later o bf16 (per-head cols)
  __shared__ unsigned short kls[64 * XBS];   // k bf16
  __shared__ unsigned short vT[128 * VTS];   // v^T bf16: vT[c][t]
  __shared__ float pS[8 * 64], pQ[8 * 64];
  __shared__ float mrow[64], vrow[64];
  int tid = threadIdx.x;
  int wv = tid >> 6, lane = tid & 63, quad = lane >> 4, lr = lane & 15;
  int f = flag[0];
  int hb = wv * 16;
  const v8s zz = {0, 0, 0, 0, 0, 0, 0, 0};
  // ---- stage x -> Xb (single copy)
  {
    size_t xoff = (size_t)b * C * N * T + (size_t)n * T;
    for (int idx = tid * 4; idx < TILE; idx += 2048) {
      int i = idx >> 6, t = idx & 63;   // t multiple of 4
      unsigned short pk[4];
      if (f) {
        float4 v4 = *(const float4*)&((const float*)xin)[xoff + (size_t)i * N * T + t];
        pk[0] = f2b(v4.x); pk[1] = f2b(v4.y); pk[2] = f2b(v4.z); pk[3] = f2b(v4.w);
      } else {
        ushort4 u4 = *(const ushort4*)&((const unsigned short*)xin)[xoff + (size_t)i * N * T + t];
        pk[0] = u4.x; pk[1] = u4.y; pk[2] = u4.z; pk[3] = u4.w;
      }
#pragma unroll
      for (int u = 0; u < 4; ++u) Xb[(t + u + 1) * XBS + i] = pk[u];
    }
    if (tid < 128) { Xb[tid] = 0; Xb[65 * XBS + tid] = 0; }
  }
  __syncthreads();
  // ---- QK conv MFMA: 3 shifted K=128 passes; wave wv -> m-tiles {2wv,2wv+1}
  {
    int mt0 = wv * 2;
    v4f acc[2][4];
#pragma unroll
    for (int mi = 0; mi < 2; ++mi)
#pragma unroll
      for (int nt = 0; nt < 4; ++nt) acc[mi][nt] = (v4f){0.f, 0.f, 0.f, 0.f};
    for (int j = 0; j < 3; ++j) {
#pragma unroll
      for (int kt = 0; kt < 4; ++kt) {
        int ko = j * 128 + kt * 32 + quad * 8;
        v8s a0 = *(const v8s*)&wqkB[(mt0 * 16 + lr) * 384 + ko];
        v8s a1 = *(const v8s*)&wqkB[((mt0 + 1) * 16 + lr) * 384 + ko];
        int bko = kt * 32 + quad * 8;
#pragma unroll
        for (int nt = 0; nt < 4; ++nt) {
          v8s bb = *(const v8s*)&Xb[(nt * 16 + lr + j) * XBS + bko];
          acc[0][nt] = __builtin_amdgcn_mfma_f32_16x16x32_bf16(a0, bb, acc[0][nt], 0, 0, 0);
          acc[1][nt] = __builtin_amdgcn_mfma_f32_16x16x32_bf16(a1, bb, acc[1][nt], 0, 0, 0);
        }
      }
    }
    unsigned short* dst = (wv < 4) ? qo : kls;
#pragma unroll
    for (int mi = 0; mi < 2; ++mi) {
      int og = (mt0 + mi) * 16 + quad * 4;
      int oo = og & 127;
#pragma unroll
      for (int nt = 0; nt < 4; ++nt) {
        int t = nt * 16 + lr;
        *(unsigned int*)&dst[t * XBS + oo] =
            pk2(acc[mi][nt][0] + bqk[og], acc[mi][nt][1] + bqk[og + 1]);
        *(unsigned int*)&dst[t * XBS + oo + 2] =
            pk2(acc[mi][nt][2] + bqk[og + 2], acc[mi][nt][3] + bqk[og + 3]);
      }
    }
  }
  // ---- V MFMA: wave wv -> o = 16wv..16wv+15, K=128; store transposed vT[o][t]
  {
    v4f av[4];
#pragma unroll
    for (int nt = 0; nt < 4; ++nt) av[nt] = (v4f){0.f, 0.f, 0.f, 0.f};
#pragma unroll
    for (int kt = 0; kt < 4; ++kt) {
      int ko = kt * 32 + quad * 8;
      v8s a = *(const v8s*)&w1B[(wv * 16 + lr) * 128 + ko];
#pragma unroll
      for (int nt = 0; nt < 4; ++nt) {
        v8s bb = *(const v8s*)&Xb[(nt * 16 + lr + 1) * XBS + ko];
        av[nt] = __builtin_amdgcn_mfma_f32_16x16x32_bf16(a, bb, av[nt], 0, 0, 0);
      }
    }
#pragma unroll
    for (int nt = 0; nt < 4; ++nt) {
      int t = nt * 16 + lr;
#pragma unroll
      for (int r = 0; r < 4; ++r) {
        int o = hb + quad * 4 + r;
        vT[o * VTS + t] = f2b(av[nt][r] + b1f[o]);
      }
    }
  }
  __syncthreads();
  // ---- temporal attention, MFMA: wave wv -> head wv (cols [hb,hb+16))
  {
    v4f sa[4][4];
#pragma unroll
    for (int ms = 0; ms < 4; ++ms)
#pragma unroll
      for (int nt = 0; nt < 4; ++nt) sa[ms][nt] = (v4f){0.f, 0.f, 0.f, 0.f};
    {
      v8s afs[4], bfs[4];
#pragma unroll
      for (int ms = 0; ms < 4; ++ms)
        afs[ms] = (quad < 2) ? *(const v8s*)&kls[(ms * 16 + lr) * XBS + hb + quad * 8] : zz;
#pragma unroll
      for (int nt = 0; nt < 4; ++nt)
        bfs[nt] = (quad < 2) ? *(const v8s*)&qo[(nt * 16 + lr) * XBS + hb + quad * 8] : zz;
#pragma unroll
      for (int ms = 0; ms < 4; ++ms)
#pragma unroll
        for (int nt = 0; nt < 4; ++nt)
          sa[ms][nt] = __builtin_amdgcn_mfma_f32_16x16x32_bf16(afs[ms], bfs[nt], sa[ms][nt], 0, 0, 0);
    }
#pragma unroll
    for (int nt = 0; nt < 4; ++nt) {
      float mx = -1e30f;
#pragma unroll
      for (int ms = 0; ms < 4; ++ms)
#pragma unroll
        for (int r = 0; r < 4; ++r) {
          float v = sa[ms][nt][r] * 0.25f;
          sa[ms][nt][r] = v;
          mx = fmaxf(mx, v);
        }
      mx = fmaxf(mx, __shfl_xor(mx, 16, 64));
      mx = fmaxf(mx, __shfl_xor(mx, 32, 64));
      float ssum = 0.f;
#pragma unroll
      for (int ms = 0; ms < 4; ++ms)
#pragma unroll
        for (int r = 0; r < 4; ++r) {
          float e = __expf(sa[ms][nt][r] - mx);
          sa[ms][nt][r] = e;
          ssum += e;
        }
      ssum += __shfl_xor(ssum, 16, 64);
      ssum += __shfl_xor(ssum, 32, 64);
      float inv = 1.f / ssum;
#pragma unroll
      for (int ms = 0; ms < 4; ++ms)
#pragma unroll
        for (int r = 0; r < 4; ++r) sa[ms][nt][r] *= inv;
    }
    v4f ov[4];
#pragma unroll
    for (int nt = 0; nt < 4; ++nt) ov[nt] = (v4f){0.f, 0.f, 0.f, 0.f};
#pragma unroll
    for (int kt = 0; kt < 2; ++kt) {
      unsigned int pA[4][2], pB[4][2];
#pragma unroll
      for (int nt = 0; nt < 4; ++nt) {
#pragma unroll
        for (int h = 0; h < 2; ++h) {
          pA[nt][h] = pk2(sa[2 * kt][nt][2 * h], sa[2 * kt][nt][2 * h + 1]);
          pB[nt][h] = pk2(sa[2 * kt + 1][nt][2 * h], sa[2 * kt + 1][nt][2 * h + 1]);
        }
      }
      v8s aV = *(const v8s*)&vT[(hb + lr) * VTS + kt * 32 + quad * 8];
#pragma unroll
      for (int nt = 0; nt < 4; ++nt) {
        union { unsigned int u[4]; v8s s; } bu;
#pragma unroll
        for (int w = 0; w < 4; ++w) {
          int src = (2 * (quad & 1) + (w >> 1)) * 16 + lr;
          unsigned int x0 = (unsigned int)__shfl((int)pA[nt][w & 1], src, 64);
          unsigned int x1 = (unsigned int)__shfl((int)pB[nt][w & 1], src, 64);
          bu.u[w] = (quad >> 1) ? x1 : x0;
        }
        ov[nt] = __builtin_amdgcn_mfma_f32_16x16x32_bf16(aV, bu.s, ov[nt], 0, 0, 0);
      }
    }
#pragma unroll
    for (int nt = 0; nt < 4; ++nt) {
      int t = nt * 16 + lr;
      *(unsigned int*)&qo[t * XBS + hb + quad * 4] = pk2(ov[nt][0], ov[nt][1]);
      *(unsigned int*)&qo[t * XBS + hb + quad * 4 + 2] = pk2(ov[nt][2], ov[nt][3]);
    }
  }
  __syncthreads();
  // ---- w2 MFMA: wave wv -> o = 16wv..+15; keep result in regs; LN partials
  v4f aw[4];
  {
#pragma unroll
    for (int nt = 0; nt < 4; ++nt) aw[nt] = (v4f){0.f, 0.f, 0.f, 0.f};
#pragma unroll
    for (int kt = 0; kt < 4; ++kt) {
      int ko = kt * 32 + quad * 8;
      v8s a = *(const v8s*)&w2B[(wv * 16 + lr) * 128 + ko];
#pragma unroll
      for (int nt = 0; nt < 4; ++nt) {
        v8s bb = *(const v8s*)&qo[(nt * 16 + lr) * XBS + ko];
        aw[nt] = __builtin_amdgcn_mfma_f32_16x16x32_bf16(a, bb, aw[nt], 0, 0, 0);
      }
    }
    int ob = hb + quad * 4;
#pragma unroll
    for (int nt = 0; nt < 4; ++nt) {
      float s = 0.f, q2 = 0.f;
#pragma unroll
      for (int r = 0; r < 4; ++r) {
        aw[nt][r] += b2f[ob + r];
        s += aw[nt][r];
        q2 += aw[nt][r] * aw[nt][r];
      }
      s += __shfl_xor(s, 16, 64);  s += __shfl_xor(s, 32, 64);
      q2 += __shfl_xor(q2, 16, 64); q2 += __shfl_xor(q2, 32, 64);
      if (quad == 0) {
        pS[wv * 64 + nt * 16 + lr] = s;
        pQ[wv * 64 + nt * 16 + lr] = q2;
      }
    }
  }
  __syncthreads();
  if (tid < 64) {
    float s = 0.f, q2 = 0.f;
#pragma unroll
    for (int w = 0; w < 8; ++w) { s += pS[w * 64 + tid]; q2 += pQ[w * 64 + tid]; }
    float mm = s * (1.f / 128.f);
    mrow[tid] = mm;
    vrow[tid] = rsqrtf(q2 * (1.f / 128.f) - mm * mm + 1e-5f);
  }
  __syncthreads();
  // ---- LN0 + residual -> g0 as hi/lo bf16 pair
  {
    int ob = hb + quad * 4;
    float gg[4], bb2[4];
#pragma unroll
    for (int r = 0; r < 4; ++r) { gg[r] = l0g[ob + r]; bb2[r] = l0b[ob + r]; }
    unsigned short* dh = g0h + (size_t)bn * TILE;
    unsigned short* dl = g0l + (size_t)bn * TILE;
#pragma unroll
    for (int nt = 0; nt < 4; ++nt) {
      int t = nt * 16 + lr;
      float m = mrow[t], rs = vrow[t];
      ushort4 xr = *(const ushort4*)&Xb[(t + 1) * XBS + ob];
      float o4[4];
      o4[0] = (aw[nt][0] - m) * rs * gg[0] + bb2[0] + bfu(xr.x);
      o4[1] = (aw[nt][1] - m) * rs * gg[1] + bb2[1] + bfu(xr.y);
      o4[2] = (aw[nt][2] - m) * rs * gg[2] + bb2[2] + bfu(xr.z);
      o4[3] = (aw[nt][3] - m) * rs * gg[3] + bb2[3] + bfu(xr.w);
      ushort4 hh, ll;
#pragma unroll
      for (int r = 0; r < 4; ++r) {
        unsigned short h = f2b(o4[r]);
        ((unsigned short*)&hh)[r] = h;
        ((unsigned short*)&ll)[r] = f2b(o4[r] - bfu(h));
      }
      *(ushort4*)&dh[t * 128 + ob] = hh;
      *(ushort4*)&dl[t * 128 + ob] = ll;
    }
  }
}

// ================================================================ megasp v6 — 1024 threads (16 waves, 4/SIMD).
// per (b,t): stage pre-split hi/lo bf16 x; QK 3-term MFMA (wave owns 16 rows);
// register softmax; PV; theta GEMM (wave = o-tile x n-half); LN1; residual
// (h+l reconstruct); write g0b bf16.
constexpr int XS = 136;   // R1/R2 row stride (ushort): 272B, 16B-aligned
constexpr int TS = 264;   // Xt row stride (ushort): 528B, 16B-aligned

__global__ __launch_bounds__(1024, 4) void k_megasp(
    const unsigned short* g0h, const unsigned short* g0l,
    const float* lap, const unsigned short* thB,
    const float* l1g, const float* l1b, const float* e, unsigned short* g0b) {
  int bt = blockIdx.x, b = bt >> 6, t = bt & 63;
  __shared__ unsigned short R1[256 * XS];   // Xhi -> P -> theta[128][136]
  __shared__ unsigned short R2[256 * XS];   // Xlo -> Xt[128][TS] -> yB[256][136]
  __shared__ float pS[8][256], pQ[8][256];
  __shared__ float mrow[256], vrow[256];
  unsigned short* Xhi = R1;
  unsigned short* Xlo = R2;
  unsigned short* Xt = R2;
  unsigned short* Pld = R1;
  int tid = threadIdx.x;
  int wv = tid >> 6, lane = tid & 63, quad = lane >> 4, lr = lane & 15;
  int wrow0 = wv * 16;
  const float sc = 0.08838834764831845f;
  // ---- stage x(b,t): pre-split hi/lo bf16 copies
  {
    size_t base = (size_t)b * (N * (size_t)TILE) + (size_t)t * 128;
    for (int idx = tid * 4; idx < 32768; idx += 4096) {
      int n = idx >> 7, c = idx & 127;
      size_t ga = base + (size_t)n * TILE + c;
      *(ushort4*)&Xhi[n * XS + c] = *(const ushort4*)&g0h[ga];
      *(ushort4*)&Xlo[n * XS + c] = *(const ushort4*)&g0l[ga];
    }
  }
  __syncthreads();
  // ---- QK: wave wv -> S rows [16wv, 16wv+16), all 256 cols, K=128
  v4f acc[16];
#pragma unroll
  for (int nt = 0; nt < 16; ++nt) acc[nt] = (v4f){0.f, 0.f, 0.f, 0.f};
  for (int kt = 0; kt < 4; ++kt) {
    int ko = kt * 32 + quad * 8;
    v8s ah0 = *(const v8s*)&Xhi[(wrow0 + lr) * XS + ko];
    v8s al0 = *(const v8s*)&Xlo[(wrow0 + lr) * XS + ko];
#pragma unroll
    for (int nt = 0; nt < 16; ++nt) {
      v8s bh = *(const v8s*)&Xhi[(nt * 16 + lr) * XS + ko];
      v8s bl = *(const v8s*)&Xlo[(nt * 16 + lr) * XS + ko];
      acc[nt] = __builtin_amdgcn_mfma_f32_16x16x32_bf16(ah0, bh, acc[nt], 0, 0, 0);
      acc[nt] = __builtin_amdgcn_mfma_f32_16x16x32_bf16(ah0, bl, acc[nt], 0, 0, 0);
      acc[nt] = __builtin_amdgcn_mfma_f32_16x16x32_bf16(al0, bh, acc[nt], 0, 0, 0);
    }
  }
  __syncthreads();
  // ---- build Xt[c][n] = Xhi[n][c] (overwrites Xlo)
  for (int task = tid; task < 8192; task += 1024) {
    int c = task & 127, n0 = (task >> 7) * 4;
    ushort4 w;
    w.x = Xhi[(n0 + 0) * XS + c];
    w.y = Xhi[(n0 + 1) * XS + c];
    w.z = Xhi[(n0 + 2) * XS + c];
    w.w = Xhi[(n0 + 3) * XS + c];
    *(ushort4*)&Xt[c * TS + n0] = w;
  }
  __syncthreads();
  // ---- softmax + Lap scale; write P half0 (cols 0..127); pack half1 in regs.
  unsigned int pk1[8][2];
#pragma unroll
  for (int r = 0; r < 4; ++r) {
    int row = wrow0 + quad * 4 + r;
    float mx = -1e30f;
#pragma unroll
    for (int nt = 0; nt < 16; ++nt) {
      acc[nt][r] *= sc;
      mx = fmaxf(mx, acc[nt][r]);
    }
#pragma unroll
    for (int m = 8; m > 0; m >>= 1) mx = fmaxf(mx, __shfl_xor(mx, m, 16));
    float ex[16];
    float ssum = 0.f;
#pragma unroll
    for (int nt = 0; nt < 16; ++nt) { ex[nt] = __expf(acc[nt][r] - mx); ssum += ex[nt]; }
#pragma unroll
    for (int m = 8; m > 0; m >>= 1) ssum += __shfl_xor(ssum, m, 16);
    float inv = sc / ssum;
    const float* lrow = lap + row * 256 + lr;
#pragma unroll
    for (int nt = 0; nt < 8; ++nt)
      Pld[row * XS + nt * 16 + lr] = f2b(ex[nt] * inv * lrow[nt * 16]);
#pragma unroll
    for (int nt = 8; nt < 16; ++nt) {
      unsigned int hbw = (unsigned int)f2b(ex[nt] * inv * lrow[nt * 16]);
      if ((r & 1) == 0) pk1[nt - 8][r >> 1] = hbw;
      else pk1[nt - 8][r >> 1] |= hbw << 16;
    }
  }
  // ---- PV: y[n][c] = sum_m P[n][m] * Xt[c][m]; two K-halves of 128.
  // P rows [wrow0,wrow0+16) are wave-private: no block barriers needed here.
  v4f acc2[8];
#pragma unroll
  for (int nt = 0; nt < 8; ++nt) acc2[nt] = (v4f){0.f, 0.f, 0.f, 0.f};
#pragma unroll
  for (int h = 0; h < 2; ++h) {
    if (h == 1) {
      int rowb = wrow0 + quad * 4;
#pragma unroll
      for (int k = 0; k < 8; ++k) {
        int col = k * 16 + lr;
        unsigned int u0 = pk1[k][0], u1 = pk1[k][1];
        Pld[(rowb + 0) * XS + col] = (unsigned short)u0;
        Pld[(rowb + 1) * XS + col] = (unsigned short)(u0 >> 16);
        Pld[(rowb + 2) * XS + col] = (unsigned short)u1;
        Pld[(rowb + 3) * XS + col] = (unsigned short)(u1 >> 16);
      }
    }
    for (int kt = 0; kt < 4; ++kt) {
      int ko = kt * 32 + quad * 8;
      v8s pa0 = *(const v8s*)&Pld[(wrow0 + lr) * XS + ko];
#pragma unroll
      for (int nt = 0; nt < 8; ++nt) {
        v8s xb = *(const v8s*)&Xt[(nt * 16 + lr) * TS + h * 128 + ko];
        acc2[nt] = __builtin_amdgcn_mfma_f32_16x16x32_bf16(pa0, xb, acc2[nt], 0, 0, 0);
      }
    }
  }
  __syncthreads();
  // ---- y -> bf16 yB (over Xt region); stage theta (over P region)
  unsigned short* yB = R2;
  unsigned short* ths = R1;
  {
    int nb = wrow0 + quad * 4;
#pragma unroll
    for (int nt = 0; nt < 8; ++nt) {
      int c = nt * 16 + lr;
#pragma unroll
      for (int r = 0; r < 4; ++r)
        yB[(nb + r) * XS + c] = f2b(acc2[nt][r]);
    }
  }
  for (int idx = tid * 8; idx < 16384; idx += 8192) {
    int o = idx >> 7, k = idx & 127;
    *(uint4*)&ths[o * 136 + k] = *(const uint4*)&thB[idx];
  }
  __syncthreads();
  // ---- theta GEMM: wave wv -> o-tile (wv&7), n-half (wv>>3)
  int ot = wv & 7, nh = wv >> 3;
  v4f acc3[8];
#pragma unroll
  for (int nt = 0; nt < 8; ++nt) acc3[nt] = (v4f){0.f, 0.f, 0.f, 0.f};
#pragma unroll
  for (int kt = 0; kt < 4; ++kt) {
    int ko = kt * 32 + quad * 8;
    v8s a = *(const v8s*)&ths[(ot * 16 + lr) * 136 + ko];
#pragma unroll
    for (int nt = 0; nt < 8; ++nt) {
      int ng = nh * 8 + nt;
      v8s bb = *(const v8s*)&yB[(ng * 16 + lr) * XS + ko];
      acc3[nt] = __builtin_amdgcn_mfma_f32_16x16x32_bf16(a, bb, acc3[nt], 0, 0, 0);
    }
  }
  // ---- relu + LN1 partials (reduce over o: in-lane 4 + cross-quad)
#pragma unroll
  for (int nt = 0; nt < 8; ++nt) {
    float s = 0.f, q2 = 0.f;
#pragma unroll
    for (int r = 0; r < 4; ++r) {
      float v = fmaxf(acc3[nt][r], 0.f);
      acc3[nt][r] = v;
      s += v; q2 += v * v;
    }
    s += __shfl_xor(s, 16, 64);  s += __shfl_xor(s, 32, 64);
    q2 += __shfl_xor(q2, 16, 64); q2 += __shfl_xor(q2, 32, 64);
    if (quad == 0) {
      int n = (nh * 8 + nt) * 16 + lr;
      pS[ot][n] = s; pQ[ot][n] = q2;
    }
  }
  __syncthreads();
  if (tid < 256) {
    float s = 0.f, q2 = 0.f;
#pragma unroll
    for (int w = 0; w < 8; ++w) { s += pS[w][tid]; q2 += pQ[w][tid]; }
    float mm = s * (1.f / 128.f);
    mrow[tid] = mm;
    vrow[tid] = rsqrtf(q2 * (1.f / 128.f) - mm * mm + 1e-5f);
  }
  __syncthreads();
  // ---- LN1 + residual (h+l) + e -> g0b (bf16)
  {
    int o0 = ot * 16 + quad * 4;
    float gg[4], bb2[4], ev[4];
    const float* eb = e + b * 128;
#pragma unroll
    for (int r = 0; r < 4; ++r) { gg[r] = l1g[o0 + r]; bb2[r] = l1b[o0 + r]; ev[r] = eb[o0 + r]; }
#pragma unroll
    for (int nt = 0; nt < 8; ++nt) {
      int n = (nh * 8 + nt) * 16 + lr;
      float m = mrow[n], rs = vrow[n];
      size_t ga = ((size_t)(b * 256 + n)) * TILE + (size_t)t * 128 + o0;
      ushort4 xh = *(const ushort4*)&g0h[ga];
      ushort4 xl = *(const ushort4*)&g0l[ga];
      ushort4 pk;
      pk.x = f2b((acc3[nt][0] - m) * rs * gg[0] + bb2[0] + bfu(xh.x) + bfu(xl.x) + ev[0]);
      pk.y = f2b((acc3[nt][1] - m) * rs * gg[1] + bb2[1] + bfu(xh.y) + bfu(xl.y) + ev[1]);
      pk.z = f2b((acc3[nt][2] - m) * rs * gg[2] + bb2[2] + bfu(xh.z) + bfu(xl.z) + ev[2]);
      pk.w = f2b((acc3[nt][3] - m) * rs * gg[3] + bb2[3] + bfu(xh.w) + bfu(xl.w) + ev[3]);
      *(ushort4*)&g0b[ga] = pk;
    }
  }
}

// ================================================================ megadec v5 — bf16 input, 40KB LDS, 3-shift convs.
__global__ __launch_bounds__(512, 4) void k_megadec(
    const unsigned short* g0b, const unsigned short* decW, const float* decb,
    const unsigned short* dxcW, const float* dxcb,
    const unsigned short* dc1W, const float* dc1b,
    const float* dp2w, const float* dp2b, const int* flag, void* outv) {
  int bn = blockIdx.x, b = bn >> 8, n = bn & 255;
  int f32o = flag[0];
  __shared__ unsigned short Xm[66 * XBS];   // enc bf16, row t+1; rows 0,65 zero
  __shared__ unsigned short E2[66 * XBS];   // ec  bf16, row t+1; rows 0,65 zero
  __shared__ float pb0[8][64], pb1[8][64];
  int tid = threadIdx.x;
  int wv = tid >> 6, lane = tid & 63, quad = lane >> 4, lr = lane & 15;
  int m0 = wv * 16;
  const unsigned short* gp = g0b + (size_t)bn * TILE;
  // ---- stage g0b -> Xm (already bf16: plain 16B copies)
  for (int idx = tid * 8; idx < TILE; idx += 4096) {
    int t = idx >> 7, c = idx & 127;
    *(uint4*)&Xm[(t + 1) * XBS + c] = *(const uint4*)&gp[idx];
  }
  if (tid < 128) {
    Xm[tid] = 0; Xm[65 * XBS + tid] = 0;
    E2[tid] = 0; E2[65 * XBS + tid] = 0;
  }
  __syncthreads();
  // ---- dec conv (3-shift): wave wv -> o = m0..m0+15
  v4f acc[4];
  float ecv[4][4];
#pragma unroll
  for (int nt = 0; nt < 4; ++nt) acc[nt] = (v4f){0.f, 0.f, 0.f, 0.f};
  for (int j = 0; j < 3; ++j) {
#pragma unroll
    for (int kt = 0; kt < 4; ++kt) {
      v8s a = *(const v8s*)&decW[(m0 + lr) * 384 + j * 128 + kt * 32 + quad * 8];
      int bko = kt * 32 + quad * 8;
#pragma unroll
      for (int nt = 0; nt < 4; ++nt) {
        v8s bb = *(const v8s*)&Xm[(nt * 16 + lr + j) * XBS + bko];
        acc[nt] = __builtin_amdgcn_mfma_f32_16x16x32_bf16(a, bb, acc[nt], 0, 0, 0);
      }
    }
  }
#pragma unroll
  for (int nt = 0; nt < 4; ++nt) {
    int t = nt * 16 + lr;
    int o = m0 + quad * 4;
    ushort4 pk;
#pragma unroll
    for (int r = 0; r < 4; ++r) {
      float v = acc[nt][r] + decb[o + r];
      ecv[nt][r] = v;
      ((unsigned short*)&pk)[r] = f2b(v);
    }
    *(ushort4*)&E2[(t + 1) * XBS + o] = pk;
  }
  __syncthreads();
  // ---- dxc conv over Xm + dc1 conv over E2 (both 3-shift)
  v4f ax[4], ac[4];
#pragma unroll
  for (int nt = 0; nt < 4; ++nt) { ax[nt] = (v4f){0.f,0.f,0.f,0.f}; ac[nt] = (v4f){0.f,0.f,0.f,0.f}; }
  for (int j = 0; j < 3; ++j) {
#pragma unroll
    for (int kt = 0; kt < 4; ++kt) {
      int wo = (m0 + lr) * 384 + j * 128 + kt * 32 + quad * 8;
      v8s a1 = *(const v8s*)&dxcW[wo];
      v8s a2 = *(const v8s*)&dc1W[wo];
      int bko = kt * 32 + quad * 8;
#pragma unroll
      for (int nt = 0; nt < 4; ++nt) {
        int row = (nt * 16 + lr + j) * XBS + bko;
        v8s b1 = *(const v8s*)&Xm[row];
        v8s b2v = *(const v8s*)&E2[row];
        ax[nt] = __builtin_amdgcn_mfma_f32_16x16x32_bf16(a1, b1, ax[nt], 0, 0, 0);
        ac[nt] = __builtin_amdgcn_mfma_f32_16x16x32_bf16(a2, b2v, ac[nt], 0, 0, 0);
      }
    }
  }
#pragma unroll
  for (int nt = 0; nt < 4; ++nt) {
    float p0 = 0.f, p1 = 0.f;
#pragma unroll
    for (int r = 0; r < 4; ++r) {
      int o = m0 + quad * 4 + r;
      float v = fmaxf(ax[nt][r] + dxcb[o] + sigm(ecv[nt][r]) + ac[nt][r] + dc1b[o], 0.f);
      p0 += v * dp2w[o];
      p1 += v * dp2w[128 + o];
    }
    p0 += __shfl_xor(p0, 16, 64); p0 += __shfl_xor(p0, 32, 64);
    p1 += __shfl_xor(p1, 16, 64); p1 += __shfl_xor(p1, 32, 64);
    if (quad == 0) { pb0[wv][nt * 16 + lr] = p0; pb1[wv][nt * 16 + lr] = p1; }
  }
  __syncthreads();
  if (tid < 128) {
    int ch = tid >> 6, t = tid & 63;
    float s = 0.f;
    if (ch == 0) { for (int w = 0; w < 8; ++w) s += pb0[w][t]; s += dp2b[0]; }
    else         { for (int w = 0; w < 8; ++w) s += pb1[w][t]; s += dp2b[1]; }
    size_t oi = ((size_t)(b * 2 + ch) * 256 + n) * 64 + t;
    if (f32o) ((float*)outv)[oi] = s;
    else ((__hip_bfloat16*)outv)[oi] = __float2bfloat16(s);
  }
}

}  // namespace

extern "C" void kernel_launch(void* const* d_in, const int* in_sizes, int n_in,
                              void* d_out, int out_size, void* d_ws, size_t ws_size,
                              hipStream_t stream) {
  (void)in_sizes; (void)n_in; (void)out_size; (void)ws_size;
  const void* x    = d_in[0];
  const void* adj  = d_in[1];
  const int*  step = (const int*)d_in[2];
  const void* wq   = d_in[3];
  const void* bq   = d_in[4];
  const void* wk   = d_in[5];
  const void* bk   = d_in[6];
  const void* w1   = d_in[7];
  const void* b1   = d_in[8];
  const void* w2   = d_in[9];
  const void* b2   = d_in[10];
  const void* th   = d_in[11];
  const void* l0g  = d_in[12];
  const void* l0b  = d_in[13];
  const void* l1g  = d_in[14];
  const void* l1b  = d_in[15];
  const void* p1w  = d_in[16];
  const void* p1b  = d_in[17];
  const void* p2w  = d_in[18];
  const void* p2b  = d_in[19];
  const void* dxcw = d_in[20];
  const void* dxcb = d_in[21];
  const void* decw = d_in[22];
  const void* decb = d_in[23];
  const void* dc1w = d_in[24];
  const void* dc1b = d_in[25];
  const void* dp2w = d_in[26];
  const void* dp2b = d_in[27];

  float* ws = (float*)d_ws;
  int* flag = (int*)ws;
  float* p = ws + 16;
  float* e     = p; p += 1024;
  float* lap   = p; p += 65536;
  float* wqkBv = p; p += 49152;   // 98304 bf16
  float* w1Bv  = p; p += 8192;    // 16384 bf16
  float* w2Bv  = p; p += 8192;
  float* thBv  = p; p += 8192;
  float* decWv = p; p += 24576;   // 49152 bf16
  float* dxcWv = p; p += 24576;
  float* dc1Wv = p; p += 24576;
  float* bqk   = p; p += 256;
  float* b1f   = p; p += 128;
  float* b2f   = p; p += 128;
  float* l0gf  = p; p += 128;
  float* l0bf  = p; p += 128;
  float* l1gf  = p; p += 128;
  float* l1bf  = p; p += 128;
  float* dxcbf = p; p += 128;
  float* decbf = p; p += 128;
  float* dc1bf = p; p += 128;
  float* dp2wf = p; p += 256;
  float* dp2bf = p; p += 8;
  size_t off = (size_t)(p - ws);
  off = (off + 127) & ~(size_t)127;
  float* xf = ws + off;                      // BIGE floats scratch
  unsigned short* g0b = (unsigned short*)xf; // bf16 xp' (BIGE ushorts, first half of xf)
  unsigned short* g0h = (unsigned short*)(xf + BIGE);  // hi bf16 (BIGE ushorts)
  unsigned short* g0l = g0h + BIGE;                    // lo bf16 (BIGE ushorts)

  PrepArgs pa;
  pa.flag = flag;
  pa.wq = wq; pa.wk = wk; pa.w1 = w1; pa.w2 = w2; pa.th = th;
  pa.dxc = dxcw; pa.dec = decw; pa.dc1 = dc1w;
  pa.bq = bq; pa.bk = bk; pa.b1 = b1; pa.b2 = b2;
  pa.l0g = l0g; pa.l0b = l0b; pa.l1g = l1g; pa.l1b = l1b;
  pa.dxcb = dxcb; pa.decb = decb; pa.dc1b = dc1b; pa.dp2w = dp2w; pa.dp2b = dp2b;
  pa.wqkB = (unsigned short*)wqkBv;
  pa.w1B = (unsigned short*)w1Bv;
  pa.w2B = (unsigned short*)w2Bv;
  pa.thB = (__hip_bfloat16*)thBv;
  pa.decWb = (unsigned short*)decWv;
  pa.dxcWb = (unsigned short*)dxcWv;
  pa.dc1Wb = (unsigned short*)dc1Wv;
  pa.bqk = bqk; pa.b1f = b1f; pa.b2f = b2f;
  pa.l0gf = l0gf; pa.l0bf = l0bf; pa.l1gf = l1gf; pa.l1bf = l1bf;
  pa.dxcbf = dxcbf; pa.decbf = decbf; pa.dc1bf = dc1bf; pa.dp2wf = dp2wf; pa.dp2bf = dp2bf;

  k_sniff<<<1, 64, 0, stream>>>((const unsigned short*)x, flag);
  k_prepall<<<200, 256, 0, stream>>>(pa, adj, lap, step, p1w, p1b, p2w, p2b, e);

  k_mega1<<<2048, 512, 0, stream>>>(x, flag, (const unsigned short*)wqkBv, bqk,
                                    (const unsigned short*)w1Bv, b1f,
                                    (const unsigned short*)w2Bv, b2f, l0gf, l0bf,
                                    g0h, g0l);
  k_megasp<<<512, 1024, 0, stream>>>(g0h, g0l, lap, (const unsigned short*)thBv,
                                     l1gf, l1bf, e, g0b);
  k_megadec<<<2048, 512, 0, stream>>>(g0b, (const unsigned short*)decWv, decbf,
                                      (const unsigned short*)dxcWv, dxcbf,
                                      (const unsigned short*)dc1Wv, dc1bf,
                                      dp2wf, dp2bf, flag, d_out);
}

// Round 7
// 411.886 us; speedup vs baseline: 1.0318x; 1.0318x over previous
//
#include <hip/hip_runtime.h>
#include <hip/hip_bf16.h>

namespace {

constexpr int C = 128, N = 256, T = 64, Bsz = 8;
constexpr int TILE = T * C;                       // 8192 elements per (b,n) slab
constexpr size_t BIGE = (size_t)Bsz * N * T * C;  // 16,777,216 elements

typedef short v8s __attribute__((ext_vector_type(8)));
typedef float v4f __attribute__((ext_vector_type(4)));

__device__ __forceinline__ float bfu(unsigned short u) {
  unsigned int x = ((unsigned int)u) << 16;
  return __uint_as_float(x);
}
__device__ __forceinline__ unsigned short f2b(float v) {
  __hip_bfloat16 h = __float2bfloat16(v);
  return *(unsigned short*)&h;
}
__device__ __forceinline__ unsigned int pk2(float a, float b) {
  return (unsigned int)f2b(a) | ((unsigned int)f2b(b) << 16);
}
// flag-aware load: f32 != 0 -> input is fp32, else bf16
__device__ __forceinline__ float ld(const void* p, size_t i, int f32) {
  if (f32) return ((const float*)p)[i];
  return bfu(((const unsigned short*)p)[i]);
}
__device__ __forceinline__ float sigm(float x) { return 1.f / (1.f + __expf(-x)); }

// ---------------------------------------------------------------- dtype sniffer
__global__ __launch_bounds__(64) void k_sniff(const unsigned short* x, int* flag) {
  __shared__ int cnt[64];
  int tid = threadIdx.x;
  int c = 0;
  for (int u = 0; u < 8; ++u) {
    unsigned short v = x[tid * 8 + u];
    int e = (v >> 7) & 255;
    c += (e >= 97 && e <= 157) ? 1 : 0;
  }
  cnt[tid] = c;
  __syncthreads();
  if (tid == 0) {
    int s = 0;
    for (int i = 0; i < 64; ++i) s += cnt[i];
    flag[0] = (s < 435) ? 1 : 0;  // <85% plausible-bf16 words -> fp32 input
  }
}

// ---------------------------------------------------------------- prep-all: weights + lap + emb in one launch
struct PrepArgs {
  const int* flag;
  const void *wq, *wk, *w1, *w2, *th, *dxc, *dec, *dc1;
  const void *bq, *bk, *b1, *b2, *l0g, *l0b, *l1g, *l1b, *dxcb, *decb, *dc1b, *dp2w, *dp2b;
  unsigned short *wqkB, *w1B, *w2B;        // bf16 [o][k]
  __hip_bfloat16* thB;                     // bf16 [o][k] (row-major, same as source)
  unsigned short *decWb, *dxcWb, *dc1Wb;   // bf16 [o][k], k = j*128+i
  float *bqk, *b1f, *b2f, *l0gf, *l0bf, *l1gf, *l1bf, *dxcbf, *decbf, *dc1bf, *dp2wf, *dp2bf;
};

// grid 200: blocks 0-127 weights, 128-191 lap (4 rows each), 192-199 emb (1 batch each)
__global__ __launch_bounds__(256) void k_prepall(
    PrepArgs a, const void* adj, float* lap, const int* step,
    const void* p1w, const void* p1b, const void* p2w, const void* p2b, float* e) {
  __shared__ float sh[256];
  __shared__ float e1[128];
  int f = a.flag[0];
  int blk = blockIdx.x, tid = threadIdx.x;
  if (blk < 128) {
    int idx = blk * 256 + tid;
    const int stride = 32768;
    // wqkB[o][k=j*128+ii], o<128 -> wq else wk. src w[(o*128+ii)*3 + j]
    for (int i = idx; i < 256 * 384; i += stride) {
      int o = i / 384, k = i - o * 384;
      int j = k >> 7, ii = k & 127;
      float v = (o < 128) ? ld(a.wq, (o * 128 + ii) * 3 + j, f)
                          : ld(a.wk, ((o - 128) * 128 + ii) * 3 + j, f);
      a.wqkB[i] = f2b(v);
    }
    for (int i = idx; i < 16384; i += stride) {
      a.w1B[i] = f2b(ld(a.w1, i, f));   // already [o][k] row-major
      a.w2B[i] = f2b(ld(a.w2, i, f));
      a.thB[i] = __float2bfloat16(ld(a.th, i, f));  // [o][k] row-major
    }
    // decoder conv weights -> bf16 [o][k = j*128 + ii]
    for (int i = idx; i < 16384; i += stride) {
      int o = i >> 7, ii = i & 127;
      int sbase = (o * 128 + ii) * 3;
#pragma unroll
      for (int j = 0; j < 3; ++j) {
        int dsti = o * 384 + j * 128 + ii;
        a.decWb[dsti] = f2b(ld(a.dec, sbase + j, f));
        a.dxcWb[dsti] = f2b(ld(a.dxc, sbase + j, f));
        a.dc1Wb[dsti] = f2b(ld(a.dc1, sbase + j, f));
      }
    }
    for (int i = idx; i < 256; i += stride) {
      a.bqk[i] = (i < 128) ? ld(a.bq, i, f) : ld(a.bk, i - 128, f);
      a.dp2wf[i] = ld(a.dp2w, i, f);
    }
    for (int i = idx; i < 128; i += stride) {
      a.b1f[i] = ld(a.b1, i, f);   a.b2f[i] = ld(a.b2, i, f);
      a.l0gf[i] = ld(a.l0g, i, f); a.l0bf[i] = ld(a.l0b, i, f);
      a.l1gf[i] = ld(a.l1g, i, f); a.l1bf[i] = ld(a.l1b, i, f);
      a.dxcbf[i] = ld(a.dxcb, i, f); a.decbf[i] = ld(a.decb, i, f); a.dc1bf[i] = ld(a.dc1b, i, f);
    }
    if (idx < 2) a.dp2bf[idx] = ld(a.dp2b, idx, f);
  } else if (blk < 192) {
    // lap: every block computes dsh (adj is L2-hot), writes its 4 rows
    float s = 0.f;
    for (int m = 0; m < 256; ++m) s += ld(adj, tid * 256 + m, f);
    sh[tid] = 1.f / sqrtf(s);
    __syncthreads();
    int n0 = (blk - 128) * 4;
    for (int idx = tid; idx < 1024; idx += 256) {
      int n = n0 + (idx >> 8), m = idx & 255;
      lap[n * 256 + m] = ld(adj, n * 256 + m, f) * sh[n] * sh[m];
    }
  } else {
    int b = blk - 192;
    if (tid < 128) {
      float sv = (float)step[b];
      int i0 = tid & 63;
      float fr = powf(10.f, (float)i0 / 63.f * 4.f);
      float ang = sv * fr;
      sh[tid] = (tid < 64) ? sinf(ang) : cosf(ang);
    }
    __syncthreads();
    if (tid < 128) {
      float aa = ld(p1b, tid, f);
      for (int i = 0; i < 128; ++i) aa += sh[i] * ld(p1w, tid * 128 + i, f);
      aa = aa * sigm(aa);
      e1[tid] = aa;
    }
    __syncthreads();
    if (tid < 128) {
      float a2 = ld(p2b, tid, f);
      for (int i = 0; i < 128; ++i) a2 += e1[i] * ld(p2w, tid * 128 + i, f);
      e[b * 128 + tid] = a2 * sigm(a2);
    }
  }
}

// ================================================================ mega1 v8 — conflict-free staging.
// Staging: thread gathers 8 channels of one t (global: 8x contiguous 128B runs
// per wave), writes ONE uint4 row-segment to LDS (2 stores/thread vs 16 scalar
// column-stores that caused ~1.2e7 bank-conflict cycles).
constexpr int XBS = 136;  // Xb row stride (u16), 272B
constexpr int VTS = 72;   // vT row stride (u16), 144B

__global__ __launch_bounds__(512, 4) void k_mega1(
    const void* xin, const int* flag,
    const unsigned short* wqkB, const float* bqk,
    const unsigned short* w1B, const float* b1f,
    const unsigned short* w2B, const float* b2f,
    const float* l0g, const float* l0b, float* g0) {
  int bn = blockIdx.x, b = bn >> 8, n = bn & 255;
  __shared__ unsigned short Xb[66 * XBS];    // x bf16, row t+1 = x[t]; rows 0,65 zero
  __shared__ unsigned short qo[64 * XBS];    // q bf16; later o bf16 (per-head cols)
  __shared__ unsigned short kls[64 * XBS];   // k bf16
  __shared__ unsigned short vT[128 * VTS];   // v^T bf16: vT[c][t]
  __shared__ float pS[8 * 64], pQ[8 * 64];
  __shared__ float mrow[64], vrow[64];
  int tid = threadIdx.x;
  int wv = tid >> 6, lane = tid & 63, quad = lane >> 4, lr = lane & 15;
  int f = flag[0];
  int hb = wv * 16;
  const v8s zz = {0, 0, 0, 0, 0, 0, 0, 0};
  // ---- stage x -> Xb: per-thread 8-channel gather, uint4 row-segment write
  {
    size_t xoff = (size_t)b * C * N * T + (size_t)n * T;
    const int NT = N * T;
    for (int idx = tid; idx < 1024; idx += 512) {
      int t = idx & 63, c0 = (idx >> 6) * 8;
      union { unsigned short us[8]; uint4 q; } pk;
      if (f) {
        const float* xp = (const float*)xin + xoff + (size_t)c0 * NT + t;
#pragma unroll
        for (int u = 0; u < 8; ++u) pk.us[u] = f2b(xp[(size_t)u * NT]);
      } else {
        const unsigned short* xp = (const unsigned short*)xin + xoff + (size_t)c0 * NT + t;
#pragma unroll
        for (int u = 0; u < 8; ++u) pk.us[u] = xp[(size_t)u * NT];
      }
      *(uint4*)&Xb[(t + 1) * XBS + c0] = pk.q;
    }
    if (tid < 128) { Xb[tid] = 0; Xb[65 * XBS + tid] = 0; }
  }
  __syncthreads();
  // ---- QK conv MFMA: 3 shifted K=128 passes; wave wv -> m-tiles {2wv,2wv+1}
  {
    int mt0 = wv * 2;
    v4f acc[2][4];
#pragma unroll
    for (int mi = 0; mi < 2; ++mi)
#pragma unroll
      for (int nt = 0; nt < 4; ++nt) acc[mi][nt] = (v4f){0.f, 0.f, 0.f, 0.f};
    for (int j = 0; j < 3; ++j) {
#pragma unroll
      for (int kt = 0; kt < 4; ++kt) {
        int ko = j * 128 + kt * 32 + quad * 8;
        v8s a0 = *(const v8s*)&wqkB[(mt0 * 16 + lr) * 384 + ko];
        v8s a1 = *(const v8s*)&wqkB[((mt0 + 1) * 16 + lr) * 384 + ko];
        int bko = kt * 32 + quad * 8;
#pragma unroll
        for (int nt = 0; nt < 4; ++nt) {
          v8s bb = *(const v8s*)&Xb[(nt * 16 + lr + j) * XBS + bko];
          acc[0][nt] = __builtin_amdgcn_mfma_f32_16x16x32_bf16(a0, bb, acc[0][nt], 0, 0, 0);
          acc[1][nt] = __builtin_amdgcn_mfma_f32_16x16x32_bf16(a1, bb, acc[1][nt], 0, 0, 0);
        }
      }
    }
    unsigned short* dst = (wv < 4) ? qo : kls;
#pragma unroll
    for (int mi = 0; mi < 2; ++mi) {
      int og = (mt0 + mi) * 16 + quad * 4;
      int oo = og & 127;
#pragma unroll
      for (int nt = 0; nt < 4; ++nt) {
        int t = nt * 16 + lr;
        *(unsigned int*)&dst[t * XBS + oo] =
            pk2(acc[mi][nt][0] + bqk[og], acc[mi][nt][1] + bqk[og + 1]);
        *(unsigned int*)&dst[t * XBS + oo + 2] =
            pk2(acc[mi][nt][2] + bqk[og + 2], acc[mi][nt][3] + bqk[og + 3]);
      }
    }
  }
  // ---- V MFMA: wave wv -> o = 16wv..16wv+15, K=128; store transposed vT[o][t]
  {
    v4f av[4];
#pragma unroll
    for (int nt = 0; nt < 4; ++nt) av[nt] = (v4f){0.f, 0.f, 0.f, 0.f};
#pragma unroll
    for (int kt = 0; kt < 4; ++kt) {
      int ko = kt * 32 + quad * 8;
      v8s a = *(const v8s*)&w1B[(wv * 16 + lr) * 128 + ko];
#pragma unroll
      for (int nt = 0; nt < 4; ++nt) {
        v8s bb = *(const v8s*)&Xb[(nt * 16 + lr + 1) * XBS + ko];
        av[nt] = __builtin_amdgcn_mfma_f32_16x16x32_bf16(a, bb, av[nt], 0, 0, 0);
      }
    }
#pragma unroll
    for (int nt = 0; nt < 4; ++nt) {
      int t = nt * 16 + lr;
#pragma unroll
      for (int r = 0; r < 4; ++r) {
        int o = hb + quad * 4 + r;
        vT[o * VTS + t] = f2b(av[nt][r] + b1f[o]);
      }
    }
  }
  __syncthreads();
  // ---- temporal attention, MFMA: wave wv -> head wv (cols [hb,hb+16))
  {
    v4f sa[4][4];
#pragma unroll
    for (int ms = 0; ms < 4; ++ms)
#pragma unroll
      for (int nt = 0; nt < 4; ++nt) sa[ms][nt] = (v4f){0.f, 0.f, 0.f, 0.f};
    {
      v8s afs[4], bfs[4];
#pragma unroll
      for (int ms = 0; ms < 4; ++ms)
        afs[ms] = (quad < 2) ? *(const v8s*)&kls[(ms * 16 + lr) * XBS + hb + quad * 8] : zz;
#pragma unroll
      for (int nt = 0; nt < 4; ++nt)
        bfs[nt] = (quad < 2) ? *(const v8s*)&qo[(nt * 16 + lr) * XBS + hb + quad * 8] : zz;
#pragma unroll
      for (int ms = 0; ms < 4; ++ms)
#pragma unroll
        for (int nt = 0; nt < 4; ++nt)
          sa[ms][nt] = __builtin_amdgcn_mfma_f32_16x16x32_bf16(afs[ms], bfs[nt], sa[ms][nt], 0, 0, 0);
    }
#pragma unroll
    for (int nt = 0; nt < 4; ++nt) {
      float mx = -1e30f;
#pragma unroll
      for (int ms = 0; ms < 4; ++ms)
#pragma unroll
        for (int r = 0; r < 4; ++r) {
          float v = sa[ms][nt][r] * 0.25f;
          sa[ms][nt][r] = v;
          mx = fmaxf(mx, v);
        }
      mx = fmaxf(mx, __shfl_xor(mx, 16, 64));
      mx = fmaxf(mx, __shfl_xor(mx, 32, 64));
      float ssum = 0.f;
#pragma unroll
      for (int ms = 0; ms < 4; ++ms)
#pragma unroll
        for (int r = 0; r < 4; ++r) {
          float e = __expf(sa[ms][nt][r] - mx);
          sa[ms][nt][r] = e;
          ssum += e;
        }
      ssum += __shfl_xor(ssum, 16, 64);
      ssum += __shfl_xor(ssum, 32, 64);
      float inv = 1.f / ssum;
#pragma unroll
      for (int ms = 0; ms < 4; ++ms)
#pragma unroll
        for (int r = 0; r < 4; ++r) sa[ms][nt][r] *= inv;
    }
    v4f ov[4];
#pragma unroll
    for (int nt = 0; nt < 4; ++nt) ov[nt] = (v4f){0.f, 0.f, 0.f, 0.f};
#pragma unroll
    for (int kt = 0; kt < 2; ++kt) {
      unsigned int pA[4][2], pB[4][2];
#pragma unroll
      for (int nt = 0; nt < 4; ++nt) {
#pragma unroll
        for (int h = 0; h < 2; ++h) {
          pA[nt][h] = pk2(sa[2 * kt][nt][2 * h], sa[2 * kt][nt][2 * h + 1]);
          pB[nt][h] = pk2(sa[2 * kt + 1][nt][2 * h], sa[2 * kt + 1][nt][2 * h + 1]);
        }
      }
      v8s aV = *(const v8s*)&vT[(hb + lr) * VTS + kt * 32 + quad * 8];
#pragma unroll
      for (int nt = 0; nt < 4; ++nt) {
        union { unsigned int u[4]; v8s s; } bu;
#pragma unroll
        for (int w = 0; w < 4; ++w) {
          int src = (2 * (quad & 1) + (w >> 1)) * 16 + lr;
          unsigned int x0 = (unsigned int)__shfl((int)pA[nt][w & 1], src, 64);
          unsigned int x1 = (unsigned int)__shfl((int)pB[nt][w & 1], src, 64);
          bu.u[w] = (quad >> 1) ? x1 : x0;
        }
        ov[nt] = __builtin_amdgcn_mfma_f32_16x16x32_bf16(aV, bu.s, ov[nt], 0, 0, 0);
      }
    }
#pragma unroll
    for (int nt = 0; nt < 4; ++nt) {
      int t = nt * 16 + lr;
      *(unsigned int*)&qo[t * XBS + hb + quad * 4] = pk2(ov[nt][0], ov[nt][1]);
      *(unsigned int*)&qo[t * XBS + hb + quad * 4 + 2] = pk2(ov[nt][2], ov[nt][3]);
    }
  }
  __syncthreads();
  // ---- w2 MFMA: wave wv -> o = 16wv..+15; keep result in regs; LN partials
  v4f aw[4];
  {
#pragma unroll
    for (int nt = 0; nt < 4; ++nt) aw[nt] = (v4f){0.f, 0.f, 0.f, 0.f};
#pragma unroll
    for (int kt = 0; kt < 4; ++kt) {
      int ko = kt * 32 + quad * 8;
      v8s a = *(const v8s*)&w2B[(wv * 16 + lr) * 128 + ko];
#pragma unroll
      for (int nt = 0; nt < 4; ++nt) {
        v8s bb = *(const v8s*)&qo[(nt * 16 + lr) * XBS + ko];
        aw[nt] = __builtin_amdgcn_mfma_f32_16x16x32_bf16(a, bb, aw[nt], 0, 0, 0);
      }
    }
    int ob = hb + quad * 4;
#pragma unroll
    for (int nt = 0; nt < 4; ++nt) {
      float s = 0.f, q2 = 0.f;
#pragma unroll
      for (int r = 0; r < 4; ++r) {
        aw[nt][r] += b2f[ob + r];
        s += aw[nt][r];
        q2 += aw[nt][r] * aw[nt][r];
      }
      s += __shfl_xor(s, 16, 64);  s += __shfl_xor(s, 32, 64);
      q2 += __shfl_xor(q2, 16, 64); q2 += __shfl_xor(q2, 32, 64);
      if (quad == 0) {
        pS[wv * 64 + nt * 16 + lr] = s;
        pQ[wv * 64 + nt * 16 + lr] = q2;
      }
    }
  }
  __syncthreads();
  if (tid < 64) {
    float s = 0.f, q2 = 0.f;
#pragma unroll
    for (int w = 0; w < 8; ++w) { s += pS[w * 64 + tid]; q2 += pQ[w * 64 + tid]; }
    float mm = s * (1.f / 128.f);
    mrow[tid] = mm;
    vrow[tid] = rsqrtf(q2 * (1.f / 128.f) - mm * mm + 1e-5f);
  }
  __syncthreads();
  // ---- LN0 + residual -> g0
  {
    int ob = hb + quad * 4;
    float gg[4], bb2[4];
#pragma unroll
    for (int r = 0; r < 4; ++r) { gg[r] = l0g[ob + r]; bb2[r] = l0b[ob + r]; }
    float* dst = g0 + (size_t)bn * TILE;
#pragma unroll
    for (int nt = 0; nt < 4; ++nt) {
      int t = nt * 16 + lr;
      float m = mrow[t], rs = vrow[t];
      ushort4 xr = *(const ushort4*)&Xb[(t + 1) * XBS + ob];
      float4 o4;
      o4.x = (aw[nt][0] - m) * rs * gg[0] + bb2[0] + bfu(xr.x);
      o4.y = (aw[nt][1] - m) * rs * gg[1] + bb2[1] + bfu(xr.y);
      o4.z = (aw[nt][2] - m) * rs * gg[2] + bb2[2] + bfu(xr.z);
      o4.w = (aw[nt][3] - m) * rs * gg[3] + bb2[3] + bfu(xr.w);
      *(float4*)&dst[t * 128 + ob] = o4;
    }
  }
}

// ================================================================ megasp v5 — fused spatial attention + theta + LN1.
// (round-5 proven version: 512 threads, in-kernel hi/lo split, bf16 g0b out)
constexpr int XS = 136;   // R1/R2 row stride (ushort): 272B, 16B-aligned
constexpr int TS = 264;   // Xt row stride (ushort): 528B, 16B-aligned

__global__ __launch_bounds__(512, 1) void k_megasp(
    const float* g0, const float* lap, const unsigned short* thB,
    const float* l1g, const float* l1b, const float* e, unsigned short* g0b) {
  int bt = blockIdx.x, b = bt >> 6, t = bt & 63;
  __shared__ unsigned short R1[256 * XS];   // Xhi -> P -> theta[128][136]
  __shared__ unsigned short R2[256 * XS];   // Xlo -> Xt[128][TS] -> yB[256][136]
  __shared__ float pS[8][256], pQ[8][256];
  __shared__ float mrow[256], vrow[256];
  unsigned short* Xhi = R1;
  unsigned short* Xlo = R2;
  unsigned short* Xt = R2;
  unsigned short* Pld = R1;
  int tid = threadIdx.x;
  int wv = tid >> 6, lane = tid & 63, quad = lane >> 4, lr = lane & 15;
  int wrow0 = wv * 32;
  const float sc = 0.08838834764831845f;
  // ---- stage x(b,t): g0 rows -> bf16 hi/lo split
  {
    size_t base = (size_t)b * (N * (size_t)TILE) + (size_t)t * 128;
    for (int idx = tid * 4; idx < 32768; idx += 2048) {
      int n = idx >> 7, c = idx & 127;
      float4 v4 = *(const float4*)&g0[base + (size_t)n * TILE + c];
      ushort4 h, l;
      h.x = f2b(v4.x); l.x = f2b(v4.x - bfu(h.x));
      h.y = f2b(v4.y); l.y = f2b(v4.y - bfu(h.y));
      h.z = f2b(v4.z); l.z = f2b(v4.z - bfu(h.z));
      h.w = f2b(v4.w); l.w = f2b(v4.w - bfu(h.w));
      *(ushort4*)&Xhi[n * XS + c] = h;
      *(ushort4*)&Xlo[n * XS + c] = l;
    }
  }
  __syncthreads();
  // ---- QK: wave wv -> S rows [32wv, 32wv+32), all 256 cols, K=128
  v4f acc[2][16];
#pragma unroll
  for (int mi = 0; mi < 2; ++mi)
#pragma unroll
    for (int nt = 0; nt < 16; ++nt) acc[mi][nt] = (v4f){0.f, 0.f, 0.f, 0.f};
  for (int kt = 0; kt < 4; ++kt) {
    int ko = kt * 32 + quad * 8;
    v8s ah0 = *(const v8s*)&Xhi[(wrow0 + lr) * XS + ko];
    v8s al0 = *(const v8s*)&Xlo[(wrow0 + lr) * XS + ko];
    v8s ah1 = *(const v8s*)&Xhi[(wrow0 + 16 + lr) * XS + ko];
    v8s al1 = *(const v8s*)&Xlo[(wrow0 + 16 + lr) * XS + ko];
#pragma unroll
    for (int nt = 0; nt < 16; ++nt) {
      v8s bh = *(const v8s*)&Xhi[(nt * 16 + lr) * XS + ko];
      v8s bl = *(const v8s*)&Xlo[(nt * 16 + lr) * XS + ko];
      acc[0][nt] = __builtin_amdgcn_mfma_f32_16x16x32_bf16(ah0, bh, acc[0][nt], 0, 0, 0);
      acc[0][nt] = __builtin_amdgcn_mfma_f32_16x16x32_bf16(ah0, bl, acc[0][nt], 0, 0, 0);
      acc[0][nt] = __builtin_amdgcn_mfma_f32_16x16x32_bf16(al0, bh, acc[0][nt], 0, 0, 0);
      acc[1][nt] = __builtin_amdgcn_mfma_f32_16x16x32_bf16(ah1, bh, acc[1][nt], 0, 0, 0);
      acc[1][nt] = __builtin_amdgcn_mfma_f32_16x16x32_bf16(ah1, bl, acc[1][nt], 0, 0, 0);
      acc[1][nt] = __builtin_amdgcn_mfma_f32_16x16x32_bf16(al1, bh, acc[1][nt], 0, 0, 0);
    }
  }
  __syncthreads();
  // ---- build Xt[c][n] = Xhi[n][c] (overwrites Xlo)
  for (int task = tid; task < 8192; task += 512) {
    int c = task & 127, n0 = (task >> 7) * 4;
    ushort4 w;
    w.x = Xhi[(n0 + 0) * XS + c];
    w.y = Xhi[(n0 + 1) * XS + c];
    w.z = Xhi[(n0 + 2) * XS + c];
    w.w = Xhi[(n0 + 3) * XS + c];
    *(ushort4*)&Xt[c * TS + n0] = w;
  }
  __syncthreads();
  // ---- softmax + Lap scale; write P half0 (cols 0..127); pack half1 in regs.
  unsigned int pk1[2][8][2];
#pragma unroll
  for (int mi = 0; mi < 2; ++mi) {
#pragma unroll
    for (int r = 0; r < 4; ++r) {
      int row = wrow0 + 16 * mi + quad * 4 + r;
      float mx = -1e30f;
#pragma unroll
      for (int nt = 0; nt < 16; ++nt) {
        acc[mi][nt][r] *= sc;
        mx = fmaxf(mx, acc[mi][nt][r]);
      }
#pragma unroll
      for (int m = 8; m > 0; m >>= 1) mx = fmaxf(mx, __shfl_xor(mx, m, 16));
      float ex[16];
      float ssum = 0.f;
#pragma unroll
      for (int nt = 0; nt < 16; ++nt) { ex[nt] = __expf(acc[mi][nt][r] - mx); ssum += ex[nt]; }
#pragma unroll
      for (int m = 8; m > 0; m >>= 1) ssum += __shfl_xor(ssum, m, 16);
      float inv = sc / ssum;
      const float* lrow = lap + row * 256 + lr;
#pragma unroll
      for (int nt = 0; nt < 8; ++nt)
        Pld[row * XS + nt * 16 + lr] = f2b(ex[nt] * inv * lrow[nt * 16]);
#pragma unroll
      for (int nt = 8; nt < 16; ++nt) {
        unsigned int hbw = (unsigned int)f2b(ex[nt] * inv * lrow[nt * 16]);
        if ((r & 1) == 0) pk1[mi][nt - 8][r >> 1] = hbw;
        else pk1[mi][nt - 8][r >> 1] |= hbw << 16;
      }
    }
  }
  // ---- PV: y[n][c] = sum_m P[n][m] * Xt[c][m]; two K-halves of 128.
  v4f acc2[2][8];
#pragma unroll
  for (int mi = 0; mi < 2; ++mi)
#pragma unroll
    for (int nt = 0; nt < 8; ++nt) acc2[mi][nt] = (v4f){0.f, 0.f, 0.f, 0.f};
#pragma unroll
  for (int h = 0; h < 2; ++h) {
    if (h == 1) {
#pragma unroll
      for (int mi = 0; mi < 2; ++mi) {
        int rowb = wrow0 + 16 * mi + quad * 4;
#pragma unroll
        for (int k = 0; k < 8; ++k) {
          int col = k * 16 + lr;
          unsigned int u0 = pk1[mi][k][0], u1 = pk1[mi][k][1];
          Pld[(rowb + 0) * XS + col] = (unsigned short)u0;
          Pld[(rowb + 1) * XS + col] = (unsigned short)(u0 >> 16);
          Pld[(rowb + 2) * XS + col] = (unsigned short)u1;
          Pld[(rowb + 3) * XS + col] = (unsigned short)(u1 >> 16);
        }
      }
    }
    for (int kt = 0; kt < 4; ++kt) {
      int ko = kt * 32 + quad * 8;
      v8s pa0 = *(const v8s*)&Pld[(wrow0 + lr) * XS + ko];
      v8s pa1 = *(const v8s*)&Pld[(wrow0 + 16 + lr) * XS + ko];
#pragma unroll
      for (int nt = 0; nt < 8; ++nt) {
        v8s xb = *(const v8s*)&Xt[(nt * 16 + lr) * TS + h * 128 + ko];
        acc2[0][nt] = __builtin_amdgcn_mfma_f32_16x16x32_bf16(pa0, xb, acc2[0][nt], 0, 0, 0);
        acc2[1][nt] = __builtin_amdgcn_mfma_f32_16x16x32_bf16(pa1, xb, acc2[1][nt], 0, 0, 0);
      }
    }
  }
  __syncthreads();
  // ---- y -> bf16 yB (over Xt region); stage theta (over P region)
  unsigned short* yB = R2;
  unsigned short* ths = R1;
#pragma unroll
  for (int mi = 0; mi < 2; ++mi) {
    int nb = wrow0 + 16 * mi + quad * 4;
#pragma unroll
    for (int nt = 0; nt < 8; ++nt) {
      int c = nt * 16 + lr;
#pragma unroll
      for (int r = 0; r < 4; ++r)
        yB[(nb + r) * XS + c] = f2b(acc2[mi][nt][r]);
    }
  }
  for (int idx = tid * 8; idx < 16384; idx += 4096) {
    int o = idx >> 7, k = idx & 127;
    *(uint4*)&ths[o * 136 + k] = *(const uint4*)&thB[idx];
  }
  __syncthreads();
  // ---- theta GEMM: wave wv -> o = [16wv,16wv+16), all 256 n
  v4f acc3[16];
#pragma unroll
  for (int nt = 0; nt < 16; ++nt) acc3[nt] = (v4f){0.f, 0.f, 0.f, 0.f};
#pragma unroll
  for (int kt = 0; kt < 4; ++kt) {
    int ko = kt * 32 + quad * 8;
    v8s a = *(const v8s*)&ths[(wv * 16 + lr) * 136 + ko];
#pragma unroll
    for (int nt = 0; nt < 16; ++nt) {
      v8s bb = *(const v8s*)&yB[(nt * 16 + lr) * XS + ko];
      acc3[nt] = __builtin_amdgcn_mfma_f32_16x16x32_bf16(a, bb, acc3[nt], 0, 0, 0);
    }
  }
  // ---- relu + LN1 partials (reduce over o: in-lane 4 + cross-quad)
#pragma unroll
  for (int nt = 0; nt < 16; ++nt) {
    float s = 0.f, q2 = 0.f;
#pragma unroll
    for (int r = 0; r < 4; ++r) {
      float v = fmaxf(acc3[nt][r], 0.f);
      acc3[nt][r] = v;
      s += v; q2 += v * v;
    }
    s += __shfl_xor(s, 16, 64);  s += __shfl_xor(s, 32, 64);
    q2 += __shfl_xor(q2, 16, 64); q2 += __shfl_xor(q2, 32, 64);
    if (quad == 0) { pS[wv][nt * 16 + lr] = s; pQ[wv][nt * 16 + lr] = q2; }
  }
  __syncthreads();
  if (tid < 256) {
    float s = 0.f, q2 = 0.f;
#pragma unroll
    for (int w = 0; w < 8; ++w) { s += pS[w][tid]; q2 += pQ[w][tid]; }
    float mm = s * (1.f / 128.f);
    mrow[tid] = mm;
    vrow[tid] = rsqrtf(q2 * (1.f / 128.f) - mm * mm + 1e-5f);
  }
  __syncthreads();
  // ---- LN1 + residual + e -> g0b (bf16; megadec consumes bf16)
  {
    int o0 = wv * 16 + quad * 4;
    float gg[4], bb2[4], ev[4];
    const float* eb = e + b * 128;
#pragma unroll
    for (int r = 0; r < 4; ++r) { gg[r] = l1g[o0 + r]; bb2[r] = l1b[o0 + r]; ev[r] = eb[o0 + r]; }
#pragma unroll
    for (int nt = 0; nt < 16; ++nt) {
      int n = nt * 16 + lr;
      float m = mrow[n], rs = vrow[n];
      size_t ga = ((size_t)(b * 256 + n)) * TILE + (size_t)t * 128 + o0;
      float4 xa = *(const float4*)&g0[ga];
      ushort4 pk;
      pk.x = f2b((acc3[nt][0] - m) * rs * gg[0] + bb2[0] + xa.x + ev[0]);
      pk.y = f2b((acc3[nt][1] - m) * rs * gg[1] + bb2[1] + xa.y + ev[1]);
      pk.z = f2b((acc3[nt][2] - m) * rs * gg[2] + bb2[2] + xa.z + ev[2]);
      pk.w = f2b((acc3[nt][3] - m) * rs * gg[3] + bb2[3] + xa.w + ev[3]);
      *(ushort4*)&g0b[ga] = pk;
    }
  }
}

// ================================================================ megadec v5 — bf16 input, 40KB LDS, 3-shift convs.
__global__ __launch_bounds__(512, 4) void k_megadec(
    const unsigned short* g0b, const unsigned short* decW, const float* decb,
    const unsigned short* dxcW, const float* dxcb,
    const unsigned short* dc1W, const float* dc1b,
    const float* dp2w, const float* dp2b, const int* flag, void* outv) {
  int bn = blockIdx.x, b = bn >> 8, n = bn & 255;
  int f32o = flag[0];
  __shared__ unsigned short Xm[66 * XBS];   // enc bf16, row t+1; rows 0,65 zero
  __shared__ unsigned short E2[66 * XBS];   // ec  bf16, row t+1; rows 0,65 zero
  __shared__ float pb0[8][64], pb1[8][64];
  int tid = threadIdx.x;
  int wv = tid >> 6, lane = tid & 63, quad = lane >> 4, lr = lane & 15;
  int m0 = wv * 16;
  const unsigned short* gp = g0b + (size_t)bn * TILE;
  // ---- stage g0b -> Xm (already bf16: plain 16B copies)
  for (int idx = tid * 8; idx < TILE; idx += 4096) {
    int t = idx >> 7, c = idx & 127;
    *(uint4*)&Xm[(t + 1) * XBS + c] = *(const uint4*)&gp[idx];
  }
  if (tid < 128) {
    Xm[tid] = 0; Xm[65 * XBS + tid] = 0;
    E2[tid] = 0; E2[65 * XBS + tid] = 0;
  }
  __syncthreads();
  // ---- dec conv (3-shift): wave wv -> o = m0..m0+15
  v4f acc[4];
  float ecv[4][4];
#pragma unroll
  for (int nt = 0; nt < 4; ++nt) acc[nt] = (v4f){0.f, 0.f, 0.f, 0.f};
  for (int j = 0; j < 3; ++j) {
#pragma unroll
    for (int kt = 0; kt < 4; ++kt) {
      v8s a = *(const v8s*)&decW[(m0 + lr) * 384 + j * 128 + kt * 32 + quad * 8];
      int bko = kt * 32 + quad * 8;
#pragma unroll
      for (int nt = 0; nt < 4; ++nt) {
        v8s bb = *(const v8s*)&Xm[(nt * 16 + lr + j) * XBS + bko];
        acc[nt] = __builtin_amdgcn_mfma_f32_16x16x32_bf16(a, bb, acc[nt], 0, 0, 0);
      }
    }
  }
#pragma unroll
  for (int nt = 0; nt < 4; ++nt) {
    int t = nt * 16 + lr;
    int o = m0 + quad * 4;
    ushort4 pk;
#pragma unroll
    for (int r = 0; r < 4; ++r) {
      float v = acc[nt][r] + decb[o + r];
      ecv[nt][r] = v;
      ((unsigned short*)&pk)[r] = f2b(v);
    }
    *(ushort4*)&E2[(t + 1) * XBS + o] = pk;
  }
  __syncthreads();
  // ---- dxc conv over Xm + dc1 conv over E2 (both 3-shift)
  v4f ax[4], ac[4];
#pragma unroll
  for (int nt = 0; nt < 4; ++nt) { ax[nt] = (v4f){0.f,0.f,0.f,0.f}; ac[nt] = (v4f){0.f,0.f,0.f,0.f}; }
  for (int j = 0; j < 3; ++j) {
#pragma unroll
    for (int kt = 0; kt < 4; ++kt) {
      int wo = (m0 + lr) * 384 + j * 128 + kt * 32 + quad * 8;
      v8s a1 = *(const v8s*)&dxcW[wo];
      v8s a2 = *(const v8s*)&dc1W[wo];
      int bko = kt * 32 + quad * 8;
#pragma unroll
      for (int nt = 0; nt < 4; ++nt) {
        int row = (nt * 16 + lr + j) * XBS + bko;
        v8s b1 = *(const v8s*)&Xm[row];
        v8s b2v = *(const v8s*)&E2[row];
        ax[nt] = __builtin_amdgcn_mfma_f32_16x16x32_bf16(a1, b1, ax[nt], 0, 0, 0);
        ac[nt] = __builtin_amdgcn_mfma_f32_16x16x32_bf16(a2, b2v, ac[nt], 0, 0, 0);
      }
    }
  }
#pragma unroll
  for (int nt = 0; nt < 4; ++nt) {
    float p0 = 0.f, p1 = 0.f;
#pragma unroll
    for (int r = 0; r < 4; ++r) {
      int o = m0 + quad * 4 + r;
      float v = fmaxf(ax[nt][r] + dxcb[o] + sigm(ecv[nt][r]) + ac[nt][r] + dc1b[o], 0.f);
      p0 += v * dp2w[o];
      p1 += v * dp2w[128 + o];
    }
    p0 += __shfl_xor(p0, 16, 64); p0 += __shfl_xor(p0, 32, 64);
    p1 += __shfl_xor(p1, 16, 64); p1 += __shfl_xor(p1, 32, 64);
    if (quad == 0) { pb0[wv][nt * 16 + lr] = p0; pb1[wv][nt * 16 + lr] = p1; }
  }
  __syncthreads();
  if (tid < 128) {
    int ch = tid >> 6, t = tid & 63;
    float s = 0.f;
    if (ch == 0) { for (int w = 0; w < 8; ++w) s += pb0[w][t]; s += dp2b[0]; }
    else         { for (int w = 0; w < 8; ++w) s += pb1[w][t]; s += dp2b[1]; }
    size_t oi = ((size_t)(b * 2 + ch) * 256 + n) * 64 + t;
    if (f32o) ((float*)outv)[oi] = s;
    else ((__hip_bfloat16*)outv)[oi] = __float2bfloat16(s);
  }
}

}  // namespace

extern "C" void kernel_launch(void* const* d_in, const int* in_sizes, int n_in,
                              void* d_out, int out_size, void* d_ws, size_t ws_size,
                              hipStream_t stream) {
  (void)in_sizes; (void)n_in; (void)out_size; (void)ws_size;
  const void* x    = d_in[0];
  const void* adj  = d_in[1];
  const int*  step = (const int*)d_in[2];
  const void* wq   = d_in[3];
  const void* bq   = d_in[4];
  const void* wk   = d_in[5];
  const void* bk   = d_in[6];
  const void* w1   = d_in[7];
  const void* b1   = d_in[8];
  const void* w2   = d_in[9];
  const void* b2   = d_in[10];
  const void* th   = d_in[11];
  const void* l0g  = d_in[12];
  const void* l0b  = d_in[13];
  const void* l1g  = d_in[14];
  const void* l1b  = d_in[15];
  const void* p1w  = d_in[16];
  const void* p1b  = d_in[17];
  const void* p2w  = d_in[18];
  const void* p2b  = d_in[19];
  const void* dxcw = d_in[20];
  const void* dxcb = d_in[21];
  const void* decw = d_in[22];
  const void* decb = d_in[23];
  const void* dc1w = d_in[24];
  const void* dc1b = d_in[25];
  const void* dp2w = d_in[26];
  const void* dp2b = d_in[27];

  float* ws = (float*)d_ws;
  int* flag = (int*)ws;
  float* p = ws + 16;
  float* e     = p; p += 1024;
  float* lap   = p; p += 65536;
  float* wqkBv = p; p += 49152;   // 98304 bf16
  float* w1Bv  = p; p += 8192;    // 16384 bf16
  float* w2Bv  = p; p += 8192;
  float* thBv  = p; p += 8192;
  float* decWv = p; p += 24576;   // 49152 bf16
  float* dxcWv = p; p += 24576;
  float* dc1Wv = p; p += 24576;
  float* bqk   = p; p += 256;
  float* b1f   = p; p += 128;
  float* b2f   = p; p += 128;
  float* l0gf  = p; p += 128;
  float* l0bf  = p; p += 128;
  float* l1gf  = p; p += 128;
  float* l1bf  = p; p += 128;
  float* dxcbf = p; p += 128;
  float* decbf = p; p += 128;
  float* dc1bf = p; p += 128;
  float* dp2wf = p; p += 256;
  float* dp2bf = p; p += 8;
  size_t off = (size_t)(p - ws);
  off = (off + 127) & ~(size_t)127;
  float* xf = ws + off;            // BIGE scratch: g0b (bf16 xp') lives here
  float* g0 = xf + BIGE;           // BIGE floats (67 MB)
  unsigned short* g0b = (unsigned short*)xf;

  PrepArgs pa;
  pa.flag = flag;
  pa.wq = wq; pa.wk = wk; pa.w1 = w1; pa.w2 = w2; pa.th = th;
  pa.dxc = dxcw; pa.dec = decw; pa.dc1 = dc1w;
  pa.bq = bq; pa.bk = bk; pa.b1 = b1; pa.b2 = b2;
  pa.l0g = l0g; pa.l0b = l0b; pa.l1g = l1g; pa.l1b = l1b;
  pa.dxcb = dxcb; pa.decb = decb; pa.dc1b = dc1b; pa.dp2w = dp2w; pa.dp2b = dp2b;
  pa.wqkB = (unsigned short*)wqkBv;
  pa.w1B = (unsigned short*)w1Bv;
  pa.w2B = (unsigned short*)w2Bv;
  pa.thB = (__hip_bfloat16*)thBv;
  pa.decWb = (unsigned short*)decWv;
  pa.dxcWb = (unsigned short*)dxcWv;
  pa.dc1Wb = (unsigned short*)dc1Wv;
  pa.bqk = bqk; pa.b1f = b1f; pa.b2f = b2f;
  pa.l0gf = l0gf; pa.l0bf = l0bf; pa.l1gf = l1gf; pa.l1bf = l1bf;
  pa.dxcbf = dxcbf; pa.decbf = decbf; pa.dc1bf = dc1bf; pa.dp2wf = dp2wf; pa.dp2bf = dp2bf;

  k_sniff<<<1, 64, 0, stream>>>((const unsigned short*)x, flag);
  k_prepall<<<200, 256, 0, stream>>>(pa, adj, lap, step, p1w, p1b, p2w, p2b, e);

  k_mega1<<<2048, 512, 0, stream>>>(x, flag, (const unsigned short*)wqkBv, bqk,
                                    (const unsigned short*)w1Bv, b1f,
                                    (const unsigned short*)w2Bv, b2f, l0gf, l0bf, g0);
  k_megasp<<<512, 512, 0, stream>>>(g0, lap, (const unsigned short*)thBv,
                                    l1gf, l1bf, e, g0b);
  k_megadec<<<2048, 512, 0, stream>>>(g0b, (const unsigned short*)decWv, decbf,
                                      (const unsigned short*)dxcWv, dxcbf,
                                      (const unsigned short*)dc1Wv, dc1bf,
                                      dp2wf, dp2bf, flag, d_out);
}

// Round 8
// 406.377 us; speedup vs baseline: 1.0458x; 1.0136x over previous
//
#include <hip/hip_runtime.h>
#include <hip/hip_bf16.h>

namespace {

constexpr int C = 128, N = 256, T = 64, Bsz = 8;
constexpr int TILE = T * C;                       // 8192 elements per (b,n) slab
constexpr size_t BIGE = (size_t)Bsz * N * T * C;  // 16,777,216 elements

typedef short v8s __attribute__((ext_vector_type(8)));
typedef float v4f __attribute__((ext_vector_type(4)));

__device__ __forceinline__ float bfu(unsigned short u) {
  unsigned int x = ((unsigned int)u) << 16;
  return __uint_as_float(x);
}
__device__ __forceinline__ unsigned short f2b(float v) {
  __hip_bfloat16 h = __float2bfloat16(v);
  return *(unsigned short*)&h;
}
__device__ __forceinline__ unsigned int pk2(float a, float b) {
  return (unsigned int)f2b(a) | ((unsigned int)f2b(b) << 16);
}
// flag-aware load: f32 != 0 -> input is fp32, else bf16
__device__ __forceinline__ float ld(const void* p, size_t i, int f32) {
  if (f32) return ((const float*)p)[i];
  return bfu(((const unsigned short*)p)[i]);
}
__device__ __forceinline__ float sigm(float x) { return 1.f / (1.f + __expf(-x)); }

// ---------------------------------------------------------------- dtype sniffer
__global__ __launch_bounds__(64) void k_sniff(const unsigned short* x, int* flag) {
  __shared__ int cnt[64];
  int tid = threadIdx.x;
  int c = 0;
  for (int u = 0; u < 8; ++u) {
    unsigned short v = x[tid * 8 + u];
    int e = (v >> 7) & 255;
    c += (e >= 97 && e <= 157) ? 1 : 0;
  }
  cnt[tid] = c;
  __syncthreads();
  if (tid == 0) {
    int s = 0;
    for (int i = 0; i < 64; ++i) s += cnt[i];
    flag[0] = (s < 435) ? 1 : 0;  // <85% plausible-bf16 words -> fp32 input
  }
}

// ---------------------------------------------------------------- dsh: coalesced row-sums of adj
// 32 blocks x 256 threads: 8 rows/block, one row per 32-lane group.
__global__ __launch_bounds__(256) void k_dsh(const void* adj, const int* flag, float* dsh) {
  int f = flag[0];
  int row = blockIdx.x * 8 + (threadIdx.x >> 5);
  int l32 = threadIdx.x & 31;
  float s = 0.f;
#pragma unroll
  for (int j = 0; j < 8; ++j) s += ld(adj, (size_t)row * 256 + l32 + j * 32, f);
#pragma unroll
  for (int m = 16; m > 0; m >>= 1) s += __shfl_xor(s, m, 32);
  if (l32 == 0) dsh[row] = 1.f / sqrtf(s);
}

// ---------------------------------------------------------------- prep-all: weights + lap + emb in one launch
struct PrepArgs {
  const int* flag;
  const void *wq, *wk, *w1, *w2, *th, *dxc, *dec, *dc1;
  const void *bq, *bk, *b1, *b2, *l0g, *l0b, *l1g, *l1b, *dxcb, *decb, *dc1b, *dp2w, *dp2b;
  unsigned short *wqkB, *w1B, *w2B;        // bf16 [o][k]
  __hip_bfloat16* thB;                     // bf16 [o][k] (row-major, same as source)
  unsigned short *decWb, *dxcWb, *dc1Wb;   // bf16 [o][k], k = j*128+i
  float *bqk, *b1f, *b2f, *l0gf, *l0bf, *l1gf, *l1bf, *dxcbf, *decbf, *dc1bf, *dp2wf, *dp2bf;
};

// grid 200: blocks 0-127 weights, 128-191 lap (4 rows each), 192-199 emb (1 batch each)
__global__ __launch_bounds__(256) void k_prepall(
    PrepArgs a, const void* adj, const float* dsh, float* lap, const int* step,
    const void* p1w, const void* p1b, const void* p2w, const void* p2b, float* e) {
  __shared__ float sh[256];
  __shared__ float e1[128];
  int f = a.flag[0];
  int blk = blockIdx.x, tid = threadIdx.x;
  if (blk < 128) {
    int idx = blk * 256 + tid;
    const int stride = 32768;
    // wqkB[o][k=j*128+ii], o<128 -> wq else wk. src w[(o*128+ii)*3 + j]
    for (int i = idx; i < 256 * 384; i += stride) {
      int o = i / 384, k = i - o * 384;
      int j = k >> 7, ii = k & 127;
      float v = (o < 128) ? ld(a.wq, (o * 128 + ii) * 3 + j, f)
                          : ld(a.wk, ((o - 128) * 128 + ii) * 3 + j, f);
      a.wqkB[i] = f2b(v);
    }
    for (int i = idx; i < 16384; i += stride) {
      a.w1B[i] = f2b(ld(a.w1, i, f));   // already [o][k] row-major
      a.w2B[i] = f2b(ld(a.w2, i, f));
      a.thB[i] = __float2bfloat16(ld(a.th, i, f));  // [o][k] row-major
    }
    // decoder conv weights -> bf16 [o][k = j*128 + ii]
    for (int i = idx; i < 16384; i += stride) {
      int o = i >> 7, ii = i & 127;
      int sbase = (o * 128 + ii) * 3;
#pragma unroll
      for (int j = 0; j < 3; ++j) {
        int dsti = o * 384 + j * 128 + ii;
        a.decWb[dsti] = f2b(ld(a.dec, sbase + j, f));
        a.dxcWb[dsti] = f2b(ld(a.dxc, sbase + j, f));
        a.dc1Wb[dsti] = f2b(ld(a.dc1, sbase + j, f));
      }
    }
    for (int i = idx; i < 256; i += stride) {
      a.bqk[i] = (i < 128) ? ld(a.bq, i, f) : ld(a.bk, i - 128, f);
      a.dp2wf[i] = ld(a.dp2w, i, f);
    }
    for (int i = idx; i < 128; i += stride) {
      a.b1f[i] = ld(a.b1, i, f);   a.b2f[i] = ld(a.b2, i, f);
      a.l0gf[i] = ld(a.l0g, i, f); a.l0bf[i] = ld(a.l0b, i, f);
      a.l1gf[i] = ld(a.l1g, i, f); a.l1bf[i] = ld(a.l1b, i, f);
      a.dxcbf[i] = ld(a.dxcb, i, f); a.decbf[i] = ld(a.decb, i, f); a.dc1bf[i] = ld(a.dc1b, i, f);
    }
    if (idx < 2) a.dp2bf[idx] = ld(a.dp2b, idx, f);
  } else if (blk < 192) {
    // lap cells: dsh precomputed by k_dsh, coalesced scale
    int n0 = (blk - 128) * 4;
    for (int idx = tid; idx < 1024; idx += 256) {
      int n = n0 + (idx >> 8), m = idx & 255;
      lap[n * 256 + m] = ld(adj, n * 256 + m, f) * dsh[n] * dsh[m];
    }
  } else {
    int b = blk - 192;
    if (tid < 128) {
      float sv = (float)step[b];
      int i0 = tid & 63;
      float fr = powf(10.f, (float)i0 / 63.f * 4.f);
      float ang = sv * fr;
      sh[tid] = (tid < 64) ? sinf(ang) : cosf(ang);
    }
    __syncthreads();
    if (tid < 128) {
      float aa = ld(p1b, tid, f);
      for (int i = 0; i < 128; ++i) aa += sh[i] * ld(p1w, tid * 128 + i, f);
      aa = aa * sigm(aa);
      e1[tid] = aa;
    }
    __syncthreads();
    if (tid < 128) {
      float a2 = ld(p2b, tid, f);
      for (int i = 0; i < 128; ++i) a2 += e1[i] * ld(p2w, tid * 128 + i, f);
      e[b * 128 + tid] = a2 * sigm(a2);
    }
  }
}

// ================================================================ mega1 v8 — conflict-free staging.
constexpr int XBS = 136;  // Xb row stride (u16), 272B
constexpr int VTS = 72;   // vT row stride (u16), 144B

__global__ __launch_bounds__(512, 4) void k_mega1(
    const void* xin, const int* flag,
    const unsigned short* wqkB, const float* bqk,
    const unsigned short* w1B, const float* b1f,
    const unsigned short* w2B, const float* b2f,
    const float* l0g, const float* l0b, float* g0) {
  int bn = blockIdx.x, b = bn >> 8, n = bn & 255;
  __shared__ unsigned short Xb[66 * XBS];    // x bf16, row t+1 = x[t]; rows 0,65 zero
  __shared__ unsigned short qo[64 * XBS];    // q bf16; later o bf16 (per-head cols)
  __shared__ unsigned short kls[64 * XBS];   // k bf16
  __shared__ unsigned short vT[128 * VTS];   // v^T bf16: vT[c][t]
  __shared__ float pS[8 * 64], pQ[8 * 64];
  __shared__ float mrow[64], vrow[64];
  int tid = threadIdx.x;
  int wv = tid >> 6, lane = tid & 63, quad = lane >> 4, lr = lane & 15;
  int f = flag[0];
  int hb = wv * 16;
  const v8s zz = {0, 0, 0, 0, 0, 0, 0, 0};
  // ---- stage x -> Xb: per-thread 8-channel gather, uint4 row-segment write
  {
    size_t xoff = (size_t)b * C * N * T + (size_t)n * T;
    const int NT = N * T;
    for (int idx = tid; idx < 1024; idx += 512) {
      int t = idx & 63, c0 = (idx >> 6) * 8;
      union { unsigned short us[8]; uint4 q; } pk;
      if (f) {
        const float* xp = (const float*)xin + xoff + (size_t)c0 * NT + t;
#pragma unroll
        for (int u = 0; u < 8; ++u) pk.us[u] = f2b(xp[(size_t)u * NT]);
      } else {
        const unsigned short* xp = (const unsigned short*)xin + xoff + (size_t)c0 * NT + t;
#pragma unroll
        for (int u = 0; u < 8; ++u) pk.us[u] = xp[(size_t)u * NT];
      }
      *(uint4*)&Xb[(t + 1) * XBS + c0] = pk.q;
    }
    if (tid < 128) { Xb[tid] = 0; Xb[65 * XBS + tid] = 0; }
  }
  __syncthreads();
  // ---- QK conv MFMA: 3 shifted K=128 passes; wave wv -> m-tiles {2wv,2wv+1}
  {
    int mt0 = wv * 2;
    v4f acc[2][4];
#pragma unroll
    for (int mi = 0; mi < 2; ++mi)
#pragma unroll
      for (int nt = 0; nt < 4; ++nt) acc[mi][nt] = (v4f){0.f, 0.f, 0.f, 0.f};
    for (int j = 0; j < 3; ++j) {
#pragma unroll
      for (int kt = 0; kt < 4; ++kt) {
        int ko = j * 128 + kt * 32 + quad * 8;
        v8s a0 = *(const v8s*)&wqkB[(mt0 * 16 + lr) * 384 + ko];
        v8s a1 = *(const v8s*)&wqkB[((mt0 + 1) * 16 + lr) * 384 + ko];
        int bko = kt * 32 + quad * 8;
#pragma unroll
        for (int nt = 0; nt < 4; ++nt) {
          v8s bb = *(const v8s*)&Xb[(nt * 16 + lr + j) * XBS + bko];
          acc[0][nt] = __builtin_amdgcn_mfma_f32_16x16x32_bf16(a0, bb, acc[0][nt], 0, 0, 0);
          acc[1][nt] = __builtin_amdgcn_mfma_f32_16x16x32_bf16(a1, bb, acc[1][nt], 0, 0, 0);
        }
      }
    }
    unsigned short* dst = (wv < 4) ? qo : kls;
#pragma unroll
    for (int mi = 0; mi < 2; ++mi) {
      int og = (mt0 + mi) * 16 + quad * 4;
      int oo = og & 127;
#pragma unroll
      for (int nt = 0; nt < 4; ++nt) {
        int t = nt * 16 + lr;
        *(unsigned int*)&dst[t * XBS + oo] =
            pk2(acc[mi][nt][0] + bqk[og], acc[mi][nt][1] + bqk[og + 1]);
        *(unsigned int*)&dst[t * XBS + oo + 2] =
            pk2(acc[mi][nt][2] + bqk[og + 2], acc[mi][nt][3] + bqk[og + 3]);
      }
    }
  }
  // ---- V MFMA: wave wv -> o = 16wv..16wv+15, K=128; store transposed vT[o][t]
  {
    v4f av[4];
#pragma unroll
    for (int nt = 0; nt < 4; ++nt) av[nt] = (v4f){0.f, 0.f, 0.f, 0.f};
#pragma unroll
    for (int kt = 0; kt < 4; ++kt) {
      int ko = kt * 32 + quad * 8;
      v8s a = *(const v8s*)&w1B[(wv * 16 + lr) * 128 + ko];
#pragma unroll
      for (int nt = 0; nt < 4; ++nt) {
        v8s bb = *(const v8s*)&Xb[(nt * 16 + lr + 1) * XBS + ko];
        av[nt] = __builtin_amdgcn_mfma_f32_16x16x32_bf16(a, bb, av[nt], 0, 0, 0);
      }
    }
#pragma unroll
    for (int nt = 0; nt < 4; ++nt) {
      int t = nt * 16 + lr;
#pragma unroll
      for (int r = 0; r < 4; ++r) {
        int o = hb + quad * 4 + r;
        vT[o * VTS + t] = f2b(av[nt][r] + b1f[o]);
      }
    }
  }
  __syncthreads();
  // ---- temporal attention, MFMA: wave wv -> head wv (cols [hb,hb+16))
  {
    v4f sa[4][4];
#pragma unroll
    for (int ms = 0; ms < 4; ++ms)
#pragma unroll
      for (int nt = 0; nt < 4; ++nt) sa[ms][nt] = (v4f){0.f, 0.f, 0.f, 0.f};
    {
      v8s afs[4], bfs[4];
#pragma unroll
      for (int ms = 0; ms < 4; ++ms)
        afs[ms] = (quad < 2) ? *(const v8s*)&kls[(ms * 16 + lr) * XBS + hb + quad * 8] : zz;
#pragma unroll
      for (int nt = 0; nt < 4; ++nt)
        bfs[nt] = (quad < 2) ? *(const v8s*)&qo[(nt * 16 + lr) * XBS + hb + quad * 8] : zz;
#pragma unroll
      for (int ms = 0; ms < 4; ++ms)
#pragma unroll
        for (int nt = 0; nt < 4; ++nt)
          sa[ms][nt] = __builtin_amdgcn_mfma_f32_16x16x32_bf16(afs[ms], bfs[nt], sa[ms][nt], 0, 0, 0);
    }
#pragma unroll
    for (int nt = 0; nt < 4; ++nt) {
      float mx = -1e30f;
#pragma unroll
      for (int ms = 0; ms < 4; ++ms)
#pragma unroll
        for (int r = 0; r < 4; ++r) {
          float v = sa[ms][nt][r] * 0.25f;
          sa[ms][nt][r] = v;
          mx = fmaxf(mx, v);
        }
      mx = fmaxf(mx, __shfl_xor(mx, 16, 64));
      mx = fmaxf(mx, __shfl_xor(mx, 32, 64));
      float ssum = 0.f;
#pragma unroll
      for (int ms = 0; ms < 4; ++ms)
#pragma unroll
        for (int r = 0; r < 4; ++r) {
          float e = __expf(sa[ms][nt][r] - mx);
          sa[ms][nt][r] = e;
          ssum += e;
        }
      ssum += __shfl_xor(ssum, 16, 64);
      ssum += __shfl_xor(ssum, 32, 64);
      float inv = 1.f / ssum;
#pragma unroll
      for (int ms = 0; ms < 4; ++ms)
#pragma unroll
        for (int r = 0; r < 4; ++r) sa[ms][nt][r] *= inv;
    }
    v4f ov[4];
#pragma unroll
    for (int nt = 0; nt < 4; ++nt) ov[nt] = (v4f){0.f, 0.f, 0.f, 0.f};
#pragma unroll
    for (int kt = 0; kt < 2; ++kt) {
      unsigned int pA[4][2], pB[4][2];
#pragma unroll
      for (int nt = 0; nt < 4; ++nt) {
#pragma unroll
        for (int h = 0; h < 2; ++h) {
          pA[nt][h] = pk2(sa[2 * kt][nt][2 * h], sa[2 * kt][nt][2 * h + 1]);
          pB[nt][h] = pk2(sa[2 * kt + 1][nt][2 * h], sa[2 * kt + 1][nt][2 * h + 1]);
        }
      }
      v8s aV = *(const v8s*)&vT[(hb + lr) * VTS + kt * 32 + quad * 8];
#pragma unroll
      for (int nt = 0; nt < 4; ++nt) {
        union { unsigned int u[4]; v8s s; } bu;
#pragma unroll
        for (int w = 0; w < 4; ++w) {
          int src = (2 * (quad & 1) + (w >> 1)) * 16 + lr;
          unsigned int x0 = (unsigned int)__shfl((int)pA[nt][w & 1], src, 64);
          unsigned int x1 = (unsigned int)__shfl((int)pB[nt][w & 1], src, 64);
          bu.u[w] = (quad >> 1) ? x1 : x0;
        }
        ov[nt] = __builtin_amdgcn_mfma_f32_16x16x32_bf16(aV, bu.s, ov[nt], 0, 0, 0);
      }
    }
#pragma unroll
    for (int nt = 0; nt < 4; ++nt) {
      int t = nt * 16 + lr;
      *(unsigned int*)&qo[t * XBS + hb + quad * 4] = pk2(ov[nt][0], ov[nt][1]);
      *(unsigned int*)&qo[t * XBS + hb + quad * 4 + 2] = pk2(ov[nt][2], ov[nt][3]);
    }
  }
  __syncthreads();
  // ---- w2 MFMA: wave wv -> o = 16wv..+15; keep result in regs; LN partials
  v4f aw[4];
  {
#pragma unroll
    for (int nt = 0; nt < 4; ++nt) aw[nt] = (v4f){0.f, 0.f, 0.f, 0.f};
#pragma unroll
    for (int kt = 0; kt < 4; ++kt) {
      int ko = kt * 32 + quad * 8;
      v8s a = *(const v8s*)&w2B[(wv * 16 + lr) * 128 + ko];
#pragma unroll
      for (int nt = 0; nt < 4; ++nt) {
        v8s bb = *(const v8s*)&qo[(nt * 16 + lr) * XBS + ko];
        aw[nt] = __builtin_amdgcn_mfma_f32_16x16x32_bf16(a, bb, aw[nt], 0, 0, 0);
      }
    }
    int ob = hb + quad * 4;
#pragma unroll
    for (int nt = 0; nt < 4; ++nt) {
      float s = 0.f, q2 = 0.f;
#pragma unroll
      for (int r = 0; r < 4; ++r) {
        aw[nt][r] += b2f[ob + r];
        s += aw[nt][r];
        q2 += aw[nt][r] * aw[nt][r];
      }
      s += __shfl_xor(s, 16, 64);  s += __shfl_xor(s, 32, 64);
      q2 += __shfl_xor(q2, 16, 64); q2 += __shfl_xor(q2, 32, 64);
      if (quad == 0) {
        pS[wv * 64 + nt * 16 + lr] = s;
        pQ[wv * 64 + nt * 16 + lr] = q2;
      }
    }
  }
  __syncthreads();
  if (tid < 64) {
    float s = 0.f, q2 = 0.f;
#pragma unroll
    for (int w = 0; w < 8; ++w) { s += pS[w * 64 + tid]; q2 += pQ[w * 64 + tid]; }
    float mm = s * (1.f / 128.f);
    mrow[tid] = mm;
    vrow[tid] = rsqrtf(q2 * (1.f / 128.f) - mm * mm + 1e-5f);
  }
  __syncthreads();
  // ---- LN0 + residual -> g0
  {
    int ob = hb + quad * 4;
    float gg[4], bb2[4];
#pragma unroll
    for (int r = 0; r < 4; ++r) { gg[r] = l0g[ob + r]; bb2[r] = l0b[ob + r]; }
    float* dst = g0 + (size_t)bn * TILE;
#pragma unroll
    for (int nt = 0; nt < 4; ++nt) {
      int t = nt * 16 + lr;
      float m = mrow[t], rs = vrow[t];
      ushort4 xr = *(const ushort4*)&Xb[(t + 1) * XBS + ob];
      float4 o4;
      o4.x = (aw[nt][0] - m) * rs * gg[0] + bb2[0] + bfu(xr.x);
      o4.y = (aw[nt][1] - m) * rs * gg[1] + bb2[1] + bfu(xr.y);
      o4.z = (aw[nt][2] - m) * rs * gg[2] + bb2[2] + bfu(xr.z);
      o4.w = (aw[nt][3] - m) * rs * gg[3] + bb2[3] + bfu(xr.w);
      *(float4*)&dst[t * 128 + ob] = o4;
    }
  }
}

// ================================================================ megasp v7 — wave-local LN1.
// theta GEMM partitioned by n (wave wv -> n rows [32wv,32wv+32), all 128 o):
// LN over o is wave-local (in-lane + 2 cross-quad shuffles) -> pS/pQ/mrow/vrow
// LDS arrays and 2 barriers removed (157KB -> 139KB LDS).
constexpr int XS = 136;   // R1/R2 row stride (ushort): 272B, 16B-aligned
constexpr int TS = 264;   // Xt row stride (ushort): 528B, 16B-aligned

__global__ __launch_bounds__(512, 1) void k_megasp(
    const float* g0, const float* lap, const unsigned short* thB,
    const float* l1g, const float* l1b, const float* e, unsigned short* g0b) {
  int bt = blockIdx.x, b = bt >> 6, t = bt & 63;
  __shared__ unsigned short R1[256 * XS];   // Xhi -> P -> theta[128][136]
  __shared__ unsigned short R2[256 * XS];   // Xlo -> Xt[128][TS] -> yB[256][136]
  unsigned short* Xhi = R1;
  unsigned short* Xlo = R2;
  unsigned short* Xt = R2;
  unsigned short* Pld = R1;
  int tid = threadIdx.x;
  int wv = tid >> 6, lane = tid & 63, quad = lane >> 4, lr = lane & 15;
  int wrow0 = wv * 32;
  const float sc = 0.08838834764831845f;
  // ---- stage x(b,t): g0 rows -> bf16 hi/lo split
  {
    size_t base = (size_t)b * (N * (size_t)TILE) + (size_t)t * 128;
    for (int idx = tid * 4; idx < 32768; idx += 2048) {
      int n = idx >> 7, c = idx & 127;
      float4 v4 = *(const float4*)&g0[base + (size_t)n * TILE + c];
      ushort4 h, l;
      h.x = f2b(v4.x); l.x = f2b(v4.x - bfu(h.x));
      h.y = f2b(v4.y); l.y = f2b(v4.y - bfu(h.y));
      h.z = f2b(v4.z); l.z = f2b(v4.z - bfu(h.z));
      h.w = f2b(v4.w); l.w = f2b(v4.w - bfu(h.w));
      *(ushort4*)&Xhi[n * XS + c] = h;
      *(ushort4*)&Xlo[n * XS + c] = l;
    }
  }
  __syncthreads();
  // ---- QK: wave wv -> S rows [32wv, 32wv+32), all 256 cols, K=128
  v4f acc[2][16];
#pragma unroll
  for (int mi = 0; mi < 2; ++mi)
#pragma unroll
    for (int nt = 0; nt < 16; ++nt) acc[mi][nt] = (v4f){0.f, 0.f, 0.f, 0.f};
  for (int kt = 0; kt < 4; ++kt) {
    int ko = kt * 32 + quad * 8;
    v8s ah0 = *(const v8s*)&Xhi[(wrow0 + lr) * XS + ko];
    v8s al0 = *(const v8s*)&Xlo[(wrow0 + lr) * XS + ko];
    v8s ah1 = *(const v8s*)&Xhi[(wrow0 + 16 + lr) * XS + ko];
    v8s al1 = *(const v8s*)&Xlo[(wrow0 + 16 + lr) * XS + ko];
#pragma unroll
    for (int nt = 0; nt < 16; ++nt) {
      v8s bh = *(const v8s*)&Xhi[(nt * 16 + lr) * XS + ko];
      v8s bl = *(const v8s*)&Xlo[(nt * 16 + lr) * XS + ko];
      acc[0][nt] = __builtin_amdgcn_mfma_f32_16x16x32_bf16(ah0, bh, acc[0][nt], 0, 0, 0);
      acc[0][nt] = __builtin_amdgcn_mfma_f32_16x16x32_bf16(ah0, bl, acc[0][nt], 0, 0, 0);
      acc[0][nt] = __builtin_amdgcn_mfma_f32_16x16x32_bf16(al0, bh, acc[0][nt], 0, 0, 0);
      acc[1][nt] = __builtin_amdgcn_mfma_f32_16x16x32_bf16(ah1, bh, acc[1][nt], 0, 0, 0);
      acc[1][nt] = __builtin_amdgcn_mfma_f32_16x16x32_bf16(ah1, bl, acc[1][nt], 0, 0, 0);
      acc[1][nt] = __builtin_amdgcn_mfma_f32_16x16x32_bf16(al1, bh, acc[1][nt], 0, 0, 0);
    }
  }
  __syncthreads();
  // ---- build Xt[c][n] = Xhi[n][c] (overwrites Xlo)
  for (int task = tid; task < 8192; task += 512) {
    int c = task & 127, n0 = (task >> 7) * 4;
    ushort4 w;
    w.x = Xhi[(n0 + 0) * XS + c];
    w.y = Xhi[(n0 + 1) * XS + c];
    w.z = Xhi[(n0 + 2) * XS + c];
    w.w = Xhi[(n0 + 3) * XS + c];
    *(ushort4*)&Xt[c * TS + n0] = w;
  }
  __syncthreads();
  // ---- softmax + Lap scale; write P half0 (cols 0..127); pack half1 in regs.
  unsigned int pk1[2][8][2];
#pragma unroll
  for (int mi = 0; mi < 2; ++mi) {
#pragma unroll
    for (int r = 0; r < 4; ++r) {
      int row = wrow0 + 16 * mi + quad * 4 + r;
      float mx = -1e30f;
#pragma unroll
      for (int nt = 0; nt < 16; ++nt) {
        acc[mi][nt][r] *= sc;
        mx = fmaxf(mx, acc[mi][nt][r]);
      }
#pragma unroll
      for (int m = 8; m > 0; m >>= 1) mx = fmaxf(mx, __shfl_xor(mx, m, 16));
      float ex[16];
      float ssum = 0.f;
#pragma unroll
      for (int nt = 0; nt < 16; ++nt) { ex[nt] = __expf(acc[mi][nt][r] - mx); ssum += ex[nt]; }
#pragma unroll
      for (int m = 8; m > 0; m >>= 1) ssum += __shfl_xor(ssum, m, 16);
      float inv = sc / ssum;
      const float* lrow = lap + row * 256 + lr;
#pragma unroll
      for (int nt = 0; nt < 8; ++nt)
        Pld[row * XS + nt * 16 + lr] = f2b(ex[nt] * inv * lrow[nt * 16]);
#pragma unroll
      for (int nt = 8; nt < 16; ++nt) {
        unsigned int hbw = (unsigned int)f2b(ex[nt] * inv * lrow[nt * 16]);
        if ((r & 1) == 0) pk1[mi][nt - 8][r >> 1] = hbw;
        else pk1[mi][nt - 8][r >> 1] |= hbw << 16;
      }
    }
  }
  // ---- PV: y[n][c] = sum_m P[n][m] * Xt[c][m]; two K-halves of 128.
  v4f acc2[2][8];
#pragma unroll
  for (int mi = 0; mi < 2; ++mi)
#pragma unroll
    for (int nt = 0; nt < 8; ++nt) acc2[mi][nt] = (v4f){0.f, 0.f, 0.f, 0.f};
#pragma unroll
  for (int h = 0; h < 2; ++h) {
    if (h == 1) {
#pragma unroll
      for (int mi = 0; mi < 2; ++mi) {
        int rowb = wrow0 + 16 * mi + quad * 4;
#pragma unroll
        for (int k = 0; k < 8; ++k) {
          int col = k * 16 + lr;
          unsigned int u0 = pk1[mi][k][0], u1 = pk1[mi][k][1];
          Pld[(rowb + 0) * XS + col] = (unsigned short)u0;
          Pld[(rowb + 1) * XS + col] = (unsigned short)(u0 >> 16);
          Pld[(rowb + 2) * XS + col] = (unsigned short)u1;
          Pld[(rowb + 3) * XS + col] = (unsigned short)(u1 >> 16);
        }
      }
    }
    for (int kt = 0; kt < 4; ++kt) {
      int ko = kt * 32 + quad * 8;
      v8s pa0 = *(const v8s*)&Pld[(wrow0 + lr) * XS + ko];
      v8s pa1 = *(const v8s*)&Pld[(wrow0 + 16 + lr) * XS + ko];
#pragma unroll
      for (int nt = 0; nt < 8; ++nt) {
        v8s xb = *(const v8s*)&Xt[(nt * 16 + lr) * TS + h * 128 + ko];
        acc2[0][nt] = __builtin_amdgcn_mfma_f32_16x16x32_bf16(pa0, xb, acc2[0][nt], 0, 0, 0);
        acc2[1][nt] = __builtin_amdgcn_mfma_f32_16x16x32_bf16(pa1, xb, acc2[1][nt], 0, 0, 0);
      }
    }
  }
  __syncthreads();
  // ---- y -> bf16 yB (over Xt region, own rows); stage theta (over P region)
  unsigned short* yB = R2;
  unsigned short* ths = R1;
#pragma unroll
  for (int mi = 0; mi < 2; ++mi) {
    int nb = wrow0 + 16 * mi + quad * 4;
#pragma unroll
    for (int nt = 0; nt < 8; ++nt) {
      int c = nt * 16 + lr;
#pragma unroll
      for (int r = 0; r < 4; ++r)
        yB[(nb + r) * XS + c] = f2b(acc2[mi][nt][r]);
    }
  }
  for (int idx = tid * 8; idx < 16384; idx += 4096) {
    int o = idx >> 7, k = idx & 127;
    *(uint4*)&ths[o * 136 + k] = *(const uint4*)&thB[idx];
  }
  __syncthreads();
  // ---- theta GEMM (n-partitioned): wave wv -> n-tiles {2wv, 2wv+1}, all 8 o-tiles
  v4f acc3[2][8];
#pragma unroll
  for (int nt2 = 0; nt2 < 2; ++nt2)
#pragma unroll
    for (int ot = 0; ot < 8; ++ot) acc3[nt2][ot] = (v4f){0.f, 0.f, 0.f, 0.f};
#pragma unroll
  for (int kt = 0; kt < 4; ++kt) {
    int ko = kt * 32 + quad * 8;
    v8s b0 = *(const v8s*)&yB[((wv * 2 + 0) * 16 + lr) * XS + ko];
    v8s b1 = *(const v8s*)&yB[((wv * 2 + 1) * 16 + lr) * XS + ko];
#pragma unroll
    for (int ot = 0; ot < 8; ++ot) {
      v8s a = *(const v8s*)&ths[(ot * 16 + lr) * 136 + ko];
      acc3[0][ot] = __builtin_amdgcn_mfma_f32_16x16x32_bf16(a, b0, acc3[0][ot], 0, 0, 0);
      acc3[1][ot] = __builtin_amdgcn_mfma_f32_16x16x32_bf16(a, b1, acc3[1][ot], 0, 0, 0);
    }
  }
  // ---- relu + wave-local LN1 (sum over o: in-lane ot,r + cross-quad shuffles)
  float mmv[2], rrv[2];
#pragma unroll
  for (int nt2 = 0; nt2 < 2; ++nt2) {
    float s = 0.f, q2 = 0.f;
#pragma unroll
    for (int ot = 0; ot < 8; ++ot)
#pragma unroll
      for (int r = 0; r < 4; ++r) {
        float v = fmaxf(acc3[nt2][ot][r], 0.f);
        acc3[nt2][ot][r] = v;
        s += v; q2 += v * v;
      }
    s += __shfl_xor(s, 16, 64);  s += __shfl_xor(s, 32, 64);
    q2 += __shfl_xor(q2, 16, 64); q2 += __shfl_xor(q2, 32, 64);
    mmv[nt2] = s * (1.f / 128.f);
    rrv[nt2] = rsqrtf(q2 * (1.f / 128.f) - mmv[nt2] * mmv[nt2] + 1e-5f);
  }
  // ---- LN1 + residual + e -> g0b (bf16; no barrier needed)
  {
    const float* eb = e + b * 128;
#pragma unroll
    for (int ot = 0; ot < 8; ++ot) {
      int o0 = ot * 16 + quad * 4;
      float gg[4], bb2[4], ev[4];
#pragma unroll
      for (int r = 0; r < 4; ++r) { gg[r] = l1g[o0 + r]; bb2[r] = l1b[o0 + r]; ev[r] = eb[o0 + r]; }
#pragma unroll
      for (int nt2 = 0; nt2 < 2; ++nt2) {
        int n = (wv * 2 + nt2) * 16 + lr;
        float m = mmv[nt2], rs = rrv[nt2];
        size_t ga = ((size_t)(b * 256 + n)) * TILE + (size_t)t * 128 + o0;
        float4 xa = *(const float4*)&g0[ga];
        ushort4 pk;
        pk.x = f2b((acc3[nt2][ot][0] - m) * rs * gg[0] + bb2[0] + xa.x + ev[0]);
        pk.y = f2b((acc3[nt2][ot][1] - m) * rs * gg[1] + bb2[1] + xa.y + ev[1]);
        pk.z = f2b((acc3[nt2][ot][2] - m) * rs * gg[2] + bb2[2] + xa.z + ev[2]);
        pk.w = f2b((acc3[nt2][ot][3] - m) * rs * gg[3] + bb2[3] + xa.w + ev[3]);
        *(ushort4*)&g0b[ga] = pk;
      }
    }
  }
}

// ================================================================ megadec v5 — bf16 input, 40KB LDS, 3-shift convs.
__global__ __launch_bounds__(512, 4) void k_megadec(
    const unsigned short* g0b, const unsigned short* decW, const float* decb,
    const unsigned short* dxcW, const float* dxcb,
    const unsigned short* dc1W, const float* dc1b,
    const float* dp2w, const float* dp2b, const int* flag, void* outv) {
  int bn = blockIdx.x, b = bn >> 8, n = bn & 255;
  int f32o = flag[0];
  __shared__ unsigned short Xm[66 * XBS];   // enc bf16, row t+1; rows 0,65 zero
  __shared__ unsigned short E2[66 * XBS];   // ec  bf16, row t+1; rows 0,65 zero
  __shared__ float pb0[8][64], pb1[8][64];
  int tid = threadIdx.x;
  int wv = tid >> 6, lane = tid & 63, quad = lane >> 4, lr = lane & 15;
  int m0 = wv * 16;
  const unsigned short* gp = g0b + (size_t)bn * TILE;
  // ---- stage g0b -> Xm (already bf16: plain 16B copies)
  for (int idx = tid * 8; idx < TILE; idx += 4096) {
    int t = idx >> 7, c = idx & 127;
    *(uint4*)&Xm[(t + 1) * XBS + c] = *(const uint4*)&gp[idx];
  }
  if (tid < 128) {
    Xm[tid] = 0; Xm[65 * XBS + tid] = 0;
    E2[tid] = 0; E2[65 * XBS + tid] = 0;
  }
  __syncthreads();
  // ---- dec conv (3-shift): wave wv -> o = m0..m0+15
  v4f acc[4];
  float ecv[4][4];
#pragma unroll
  for (int nt = 0; nt < 4; ++nt) acc[nt] = (v4f){0.f, 0.f, 0.f, 0.f};
  for (int j = 0; j < 3; ++j) {
#pragma unroll
    for (int kt = 0; kt < 4; ++kt) {
      v8s a = *(const v8s*)&decW[(m0 + lr) * 384 + j * 128 + kt * 32 + quad * 8];
      int bko = kt * 32 + quad * 8;
#pragma unroll
      for (int nt = 0; nt < 4; ++nt) {
        v8s bb = *(const v8s*)&Xm[(nt * 16 + lr + j) * XBS + bko];
        acc[nt] = __builtin_amdgcn_mfma_f32_16x16x32_bf16(a, bb, acc[nt], 0, 0, 0);
      }
    }
  }
#pragma unroll
  for (int nt = 0; nt < 4; ++nt) {
    int t = nt * 16 + lr;
    int o = m0 + quad * 4;
    ushort4 pk;
#pragma unroll
    for (int r = 0; r < 4; ++r) {
      float v = acc[nt][r] + decb[o + r];
      ecv[nt][r] = v;
      ((unsigned short*)&pk)[r] = f2b(v);
    }
    *(ushort4*)&E2[(t + 1) * XBS + o] = pk;
  }
  __syncthreads();
  // ---- dxc conv over Xm + dc1 conv over E2 (both 3-shift)
  v4f ax[4], ac[4];
#pragma unroll
  for (int nt = 0; nt < 4; ++nt) { ax[nt] = (v4f){0.f,0.f,0.f,0.f}; ac[nt] = (v4f){0.f,0.f,0.f,0.f}; }
  for (int j = 0; j < 3; ++j) {
#pragma unroll
    for (int kt = 0; kt < 4; ++kt) {
      int wo = (m0 + lr) * 384 + j * 128 + kt * 32 + quad * 8;
      v8s a1 = *(const v8s*)&dxcW[wo];
      v8s a2 = *(const v8s*)&dc1W[wo];
      int bko = kt * 32 + quad * 8;
#pragma unroll
      for (int nt = 0; nt < 4; ++nt) {
        int row = (nt * 16 + lr + j) * XBS + bko;
        v8s b1 = *(const v8s*)&Xm[row];
        v8s b2v = *(const v8s*)&E2[row];
        ax[nt] = __builtin_amdgcn_mfma_f32_16x16x32_bf16(a1, b1, ax[nt], 0, 0, 0);
        ac[nt] = __builtin_amdgcn_mfma_f32_16x16x32_bf16(a2, b2v, ac[nt], 0, 0, 0);
      }
    }
  }
#pragma unroll
  for (int nt = 0; nt < 4; ++nt) {
    float p0 = 0.f, p1 = 0.f;
#pragma unroll
    for (int r = 0; r < 4; ++r) {
      int o = m0 + quad * 4 + r;
      float v = fmaxf(ax[nt][r] + dxcb[o] + sigm(ecv[nt][r]) + ac[nt][r] + dc1b[o], 0.f);
      p0 += v * dp2w[o];
      p1 += v * dp2w[128 + o];
    }
    p0 += __shfl_xor(p0, 16, 64); p0 += __shfl_xor(p0, 32, 64);
    p1 += __shfl_xor(p1, 16, 64); p1 += __shfl_xor(p1, 32, 64);
    if (quad == 0) { pb0[wv][nt * 16 + lr] = p0; pb1[wv][nt * 16 + lr] = p1; }
  }
  __syncthreads();
  if (tid < 128) {
    int ch = tid >> 6, t = tid & 63;
    float s = 0.f;
    if (ch == 0) { for (int w = 0; w < 8; ++w) s += pb0[w][t]; s += dp2b[0]; }
    else         { for (int w = 0; w < 8; ++w) s += pb1[w][t]; s += dp2b[1]; }
    size_t oi = ((size_t)(b * 2 + ch) * 256 + n) * 64 + t;
    if (f32o) ((float*)outv)[oi] = s;
    else ((__hip_bfloat16*)outv)[oi] = __float2bfloat16(s);
  }
}

}  // namespace

extern "C" void kernel_launch(void* const* d_in, const int* in_sizes, int n_in,
                              void* d_out, int out_size, void* d_ws, size_t ws_size,
                              hipStream_t stream) {
  (void)in_sizes; (void)n_in; (void)out_size; (void)ws_size;
  const void* x    = d_in[0];
  const void* adj  = d_in[1];
  const int*  step = (const int*)d_in[2];
  const void* wq   = d_in[3];
  const void* bq   = d_in[4];
  const void* wk   = d_in[5];
  const void* bk   = d_in[6];
  const void* w1   = d_in[7];
  const void* b1   = d_in[8];
  const void* w2   = d_in[9];
  const void* b2   = d_in[10];
  const void* th   = d_in[11];
  const void* l0g  = d_in[12];
  const void* l0b  = d_in[13];
  const void* l1g  = d_in[14];
  const void* l1b  = d_in[15];
  const void* p1w  = d_in[16];
  const void* p1b  = d_in[17];
  const void* p2w  = d_in[18];
  const void* p2b  = d_in[19];
  const void* dxcw = d_in[20];
  const void* dxcb = d_in[21];
  const void* decw = d_in[22];
  const void* decb = d_in[23];
  const void* dc1w = d_in[24];
  const void* dc1b = d_in[25];
  const void* dp2w = d_in[26];
  const void* dp2b = d_in[27];

  float* ws = (float*)d_ws;
  int* flag = (int*)ws;
  float* p = ws + 16;
  float* e     = p; p += 1024;
  float* lap   = p; p += 65536;
  float* dshv  = p; p += 256;
  float* wqkBv = p; p += 49152;   // 98304 bf16
  float* w1Bv  = p; p += 8192;    // 16384 bf16
  float* w2Bv  = p; p += 8192;
  float* thBv  = p; p += 8192;
  float* decWv = p; p += 24576;   // 49152 bf16
  float* dxcWv = p; p += 24576;
  float* dc1Wv = p; p += 24576;
  float* bqk   = p; p += 256;
  float* b1f   = p; p += 128;
  float* b2f   = p; p += 128;
  float* l0gf  = p; p += 128;
  float* l0bf  = p; p += 128;
  float* l1gf  = p; p += 128;
  float* l1bf  = p; p += 128;
  float* dxcbf = p; p += 128;
  float* decbf = p; p += 128;
  float* dc1bf = p; p += 128;
  float* dp2wf = p; p += 256;
  float* dp2bf = p; p += 8;
  size_t off = (size_t)(p - ws);
  off = (off + 127) & ~(size_t)127;
  float* xf = ws + off;            // BIGE scratch: g0b (bf16 xp') lives here
  float* g0 = xf + BIGE;           // BIGE floats (67 MB)
  unsigned short* g0b = (unsigned short*)xf;

  PrepArgs pa;
  pa.flag = flag;
  pa.wq = wq; pa.wk = wk; pa.w1 = w1; pa.w2 = w2; pa.th = th;
  pa.dxc = dxcw; pa.dec = decw; pa.dc1 = dc1w;
  pa.bq = bq; pa.bk = bk; pa.b1 = b1; pa.b2 = b2;
  pa.l0g = l0g; pa.l0b = l0b; pa.l1g = l1g; pa.l1b = l1b;
  pa.dxcb = dxcb; pa.decb = decb; pa.dc1b = dc1b; pa.dp2w = dp2w; pa.dp2b = dp2b;
  pa.wqkB = (unsigned short*)wqkBv;
  pa.w1B = (unsigned short*)w1Bv;
  pa.w2B = (unsigned short*)w2Bv;
  pa.thB = (__hip_bfloat16*)thBv;
  pa.decWb = (unsigned short*)decWv;
  pa.dxcWb = (unsigned short*)dxcWv;
  pa.dc1Wb = (unsigned short*)dc1Wv;
  pa.bqk = bqk; pa.b1f = b1f; pa.b2f = b2f;
  pa.l0gf = l0gf; pa.l0bf = l0bf; pa.l1gf = l1gf; pa.l1bf = l1bf;
  pa.dxcbf = dxcbf; pa.decbf = decbf; pa.dc1bf = dc1bf; pa.dp2wf = dp2wf; pa.dp2bf = dp2bf;

  k_sniff<<<1, 64, 0, stream>>>((const unsigned short*)x, flag);
  k_dsh<<<32, 256, 0, stream>>>(adj, flag, dshv);
  k_prepall<<<200, 256, 0, stream>>>(pa, adj, dshv, lap, step, p1w, p1b, p2w, p2b, e);

  k_mega1<<<2048, 512, 0, stream>>>(x, flag, (const unsigned short*)wqkBv, bqk,
                                    (const unsigned short*)w1Bv, b1f,
                                    (const unsigned short*)w2Bv, b2f, l0gf, l0bf, g0);
  k_megasp<<<512, 512, 0, stream>>>(g0, lap, (const unsigned short*)thBv,
                                    l1gf, l1bf, e, g0b);
  k_megadec<<<2048, 512, 0, stream>>>(g0b, (const unsigned short*)decWv, decbf,
                                      (const unsigned short*)dxcWv, dxcbf,
                                      (const unsigned short*)dc1Wv, dc1bf,
                                      dp2wf, dp2bf, flag, d_out);
}

// Round 9
// 400.662 us; speedup vs baseline: 1.0607x; 1.0143x over previous
//
#include <hip/hip_runtime.h>
#include <hip/hip_bf16.h>

namespace {

constexpr int C = 128, N = 256, T = 64, Bsz = 8;
constexpr int TILE = T * C;                       // 8192 elements per (b,n) slab
constexpr size_t BIGE = (size_t)Bsz * N * T * C;  // 16,777,216 elements

typedef short v8s __attribute__((ext_vector_type(8)));
typedef float v4f __attribute__((ext_vector_type(4)));

__device__ __forceinline__ float bfu(unsigned short u) {
  unsigned int x = ((unsigned int)u) << 16;
  return __uint_as_float(x);
}
__device__ __forceinline__ unsigned short f2b(float v) {
  __hip_bfloat16 h = __float2bfloat16(v);
  return *(unsigned short*)&h;
}
__device__ __forceinline__ unsigned int pk2(float a, float b) {
  return (unsigned int)f2b(a) | ((unsigned int)f2b(b) << 16);
}
// flag-aware load: f32 != 0 -> input is fp32, else bf16
__device__ __forceinline__ float ld(const void* p, size_t i, int f32) {
  if (f32) return ((const float*)p)[i];
  return bfu(((const unsigned short*)p)[i]);
}
__device__ __forceinline__ float sigm(float x) { return 1.f / (1.f + __expf(-x)); }

// ---------------------------------------------------------------- dtype sniffer
__global__ __launch_bounds__(64) void k_sniff(const unsigned short* x, int* flag) {
  __shared__ int cnt[64];
  int tid = threadIdx.x;
  int c = 0;
  for (int u = 0; u < 8; ++u) {
    unsigned short v = x[tid * 8 + u];
    int e = (v >> 7) & 255;
    c += (e >= 97 && e <= 157) ? 1 : 0;
  }
  cnt[tid] = c;
  __syncthreads();
  if (tid == 0) {
    int s = 0;
    for (int i = 0; i < 64; ++i) s += cnt[i];
    flag[0] = (s < 435) ? 1 : 0;  // <85% plausible-bf16 words -> fp32 input
  }
}

// ---------------------------------------------------------------- dsh: coalesced row-sums of adj
__global__ __launch_bounds__(256) void k_dsh(const void* adj, const int* flag, float* dsh) {
  int f = flag[0];
  int row = blockIdx.x * 8 + (threadIdx.x >> 5);
  int l32 = threadIdx.x & 31;
  float s = 0.f;
#pragma unroll
  for (int j = 0; j < 8; ++j) s += ld(adj, (size_t)row * 256 + l32 + j * 32, f);
#pragma unroll
  for (int m = 16; m > 0; m >>= 1) s += __shfl_xor(s, m, 32);
  if (l32 == 0) dsh[row] = 1.f / sqrtf(s);
}

// ---------------------------------------------------------------- prep-all: weights + lap + emb in one launch
struct PrepArgs {
  const int* flag;
  const void *wq, *wk, *w1, *w2, *th, *dxc, *dec, *dc1;
  const void *bq, *bk, *b1, *b2, *l0g, *l0b, *l1g, *l1b, *dxcb, *decb, *dc1b, *dp2w, *dp2b;
  unsigned short *wqkB, *w1B, *w2B;        // bf16 [o][k]
  __hip_bfloat16* thB;                     // bf16 [o][k] (row-major, same as source)
  unsigned short *decWb, *dxcWb, *dc1Wb;   // bf16 [o][k], k = j*128+i
  float *bqk, *b1f, *b2f, *l0gf, *l0bf, *l1gf, *l1bf, *dxcbf, *decbf, *dc1bf, *dp2wf, *dp2bf;
};

// grid 200: blocks 0-127 weights, 128-191 lap (4 rows each), 192-199 emb (1 batch each)
__global__ __launch_bounds__(256) void k_prepall(
    PrepArgs a, const void* adj, const float* dsh, float* lap, const int* step,
    const void* p1w, const void* p1b, const void* p2w, const void* p2b, float* e) {
  __shared__ float sh[256];
  __shared__ float e1[128];
  int f = a.flag[0];
  int blk = blockIdx.x, tid = threadIdx.x;
  if (blk < 128) {
    int idx = blk * 256 + tid;
    const int stride = 32768;
    for (int i = idx; i < 256 * 384; i += stride) {
      int o = i / 384, k = i - o * 384;
      int j = k >> 7, ii = k & 127;
      float v = (o < 128) ? ld(a.wq, (o * 128 + ii) * 3 + j, f)
                          : ld(a.wk, ((o - 128) * 128 + ii) * 3 + j, f);
      a.wqkB[i] = f2b(v);
    }
    for (int i = idx; i < 16384; i += stride) {
      a.w1B[i] = f2b(ld(a.w1, i, f));
      a.w2B[i] = f2b(ld(a.w2, i, f));
      a.thB[i] = __float2bfloat16(ld(a.th, i, f));
    }
    for (int i = idx; i < 16384; i += stride) {
      int o = i >> 7, ii = i & 127;
      int sbase = (o * 128 + ii) * 3;
#pragma unroll
      for (int j = 0; j < 3; ++j) {
        int dsti = o * 384 + j * 128 + ii;
        a.decWb[dsti] = f2b(ld(a.dec, sbase + j, f));
        a.dxcWb[dsti] = f2b(ld(a.dxc, sbase + j, f));
        a.dc1Wb[dsti] = f2b(ld(a.dc1, sbase + j, f));
      }
    }
    for (int i = idx; i < 256; i += stride) {
      a.bqk[i] = (i < 128) ? ld(a.bq, i, f) : ld(a.bk, i - 128, f);
      a.dp2wf[i] = ld(a.dp2w, i, f);
    }
    for (int i = idx; i < 128; i += stride) {
      a.b1f[i] = ld(a.b1, i, f);   a.b2f[i] = ld(a.b2, i, f);
      a.l0gf[i] = ld(a.l0g, i, f); a.l0bf[i] = ld(a.l0b, i, f);
      a.l1gf[i] = ld(a.l1g, i, f); a.l1bf[i] = ld(a.l1b, i, f);
      a.dxcbf[i] = ld(a.dxcb, i, f); a.decbf[i] = ld(a.decb, i, f); a.dc1bf[i] = ld(a.dc1b, i, f);
    }
    if (idx < 2) a.dp2bf[idx] = ld(a.dp2b, idx, f);
  } else if (blk < 192) {
    int n0 = (blk - 128) * 4;
    for (int idx = tid; idx < 1024; idx += 256) {
      int n = n0 + (idx >> 8), m = idx & 255;
      lap[n * 256 + m] = ld(adj, n * 256 + m, f) * dsh[n] * dsh[m];
    }
  } else {
    int b = blk - 192;
    if (tid < 128) {
      float sv = (float)step[b];
      int i0 = tid & 63;
      float fr = powf(10.f, (float)i0 / 63.f * 4.f);
      float ang = sv * fr;
      sh[tid] = (tid < 64) ? sinf(ang) : cosf(ang);
    }
    __syncthreads();
    if (tid < 128) {
      float aa = ld(p1b, tid, f);
      for (int i = 0; i < 128; ++i) aa += sh[i] * ld(p1w, tid * 128 + i, f);
      aa = aa * sigm(aa);
      e1[tid] = aa;
    }
    __syncthreads();
    if (tid < 128) {
      float a2 = ld(p2b, tid, f);
      for (int i = 0; i < 128; ++i) a2 += e1[i] * ld(p2w, tid * 128 + i, f);
      e[b * 128 + tid] = a2 * sigm(a2);
    }
  }
}

// ================================================================ mega1 v9 — register q/k, barrier-free middle.
// QK m-tiles {wv, 8+wv}: head wv's q AND k stay in this wave's registers
// (packed bf16); attention A/B frags built via 32 intra-wave shuffles.
// kls deleted; Xb 65 rows (zero rows 0/65 share row 0 via j=2 remap).
// Barriers: stage -> [QK,V,attn,o-write] -> w2 -> stats -> out  (4 total).
constexpr int XBS = 136;  // Xb/qo row stride (u16), 272B
constexpr int VTS = 72;   // vT row stride (u16), 144B

__global__ __launch_bounds__(512, 4) void k_mega1(
    const void* xin, const int* flag,
    const unsigned short* wqkB, const float* bqk,
    const unsigned short* w1B, const float* b1f,
    const unsigned short* w2B, const float* b2f,
    const float* l0g, const float* l0b, float* g0) {
  int bn = blockIdx.x, b = bn >> 8, n = bn & 255;
  __shared__ unsigned short Xb[65 * XBS];    // row p = x[p-1]; row 0 zero (also x[64])
  __shared__ unsigned short qo[64 * XBS];    // o bf16 (attention output)
  __shared__ unsigned short vT[128 * VTS];   // v^T bf16: vT[c][t]
  __shared__ float pS[8 * 64], pQ[8 * 64];
  __shared__ float mrow[64], vrow[64];
  int tid = threadIdx.x;
  int wv = tid >> 6, lane = tid & 63, quad = lane >> 4, lr = lane & 15;
  int f = flag[0];
  int hb = wv * 16;
  // ---- stage x -> Xb: per-thread 8-channel gather, uint4 row-segment write
  {
    size_t xoff = (size_t)b * C * N * T + (size_t)n * T;
    const int NT = N * T;
    for (int idx = tid; idx < 1024; idx += 512) {
      int t = idx & 63, c0 = (idx >> 6) * 8;
      union { unsigned short us[8]; uint4 q; } pk;
      if (f) {
        const float* xp = (const float*)xin + xoff + (size_t)c0 * NT + t;
#pragma unroll
        for (int u = 0; u < 8; ++u) pk.us[u] = f2b(xp[(size_t)u * NT]);
      } else {
        const unsigned short* xp = (const unsigned short*)xin + xoff + (size_t)c0 * NT + t;
#pragma unroll
        for (int u = 0; u < 8; ++u) pk.us[u] = xp[(size_t)u * NT];
      }
      *(uint4*)&Xb[(t + 1) * XBS + c0] = pk.q;
    }
    if (tid < 128) Xb[tid] = 0;
  }
  __syncthreads();
  // ---- QK conv MFMA: m-tiles {wv (q-head), 8+wv (k-head)}; 3 shifted K=128 passes
  unsigned int pkq[4][2], pkk[4][2];
  {
    v4f acc[2][4];
#pragma unroll
    for (int mi = 0; mi < 2; ++mi)
#pragma unroll
      for (int nt = 0; nt < 4; ++nt) acc[mi][nt] = (v4f){0.f, 0.f, 0.f, 0.f};
    for (int j = 0; j < 3; ++j) {
#pragma unroll
      for (int kt = 0; kt < 4; ++kt) {
        int ko = j * 128 + kt * 32 + quad * 8;
        v8s a0 = *(const v8s*)&wqkB[(wv * 16 + lr) * 384 + ko];
        v8s a1 = *(const v8s*)&wqkB[((8 + wv) * 16 + lr) * 384 + ko];
        int bko = kt * 32 + quad * 8;
#pragma unroll
        for (int nt = 0; nt < 4; ++nt) {
          int rr = nt * 16 + lr + j;
          rr = (rr == 65) ? 0 : rr;
          v8s bb = *(const v8s*)&Xb[rr * XBS + bko];
          acc[0][nt] = __builtin_amdgcn_mfma_f32_16x16x32_bf16(a0, bb, acc[0][nt], 0, 0, 0);
          acc[1][nt] = __builtin_amdgcn_mfma_f32_16x16x32_bf16(a1, bb, acc[1][nt], 0, 0, 0);
        }
      }
    }
    // pack q/k (+bias) to bf16 pairs in registers; acc[.][nt][r] = val[o=tile*16+quad*4+r][t=nt*16+lr]
    int oq = wv * 16 + quad * 4;
#pragma unroll
    for (int nt = 0; nt < 4; ++nt) {
#pragma unroll
      for (int h = 0; h < 2; ++h) {
        pkq[nt][h] = pk2(acc[0][nt][2 * h] + bqk[oq + 2 * h],
                         acc[0][nt][2 * h + 1] + bqk[oq + 2 * h + 1]);
        pkk[nt][h] = pk2(acc[1][nt][2 * h] + bqk[128 + oq + 2 * h],
                         acc[1][nt][2 * h + 1] + bqk[128 + oq + 2 * h + 1]);
      }
    }
  }
  // ---- V MFMA: wave wv -> o = 16wv..16wv+15, K=128; store transposed vT[o][t] (wave-private)
  {
    v4f av[4];
#pragma unroll
    for (int nt = 0; nt < 4; ++nt) av[nt] = (v4f){0.f, 0.f, 0.f, 0.f};
#pragma unroll
    for (int kt = 0; kt < 4; ++kt) {
      int ko = kt * 32 + quad * 8;
      v8s a = *(const v8s*)&w1B[(wv * 16 + lr) * 128 + ko];
#pragma unroll
      for (int nt = 0; nt < 4; ++nt) {
        v8s bb = *(const v8s*)&Xb[(nt * 16 + lr + 1) * XBS + ko];
        av[nt] = __builtin_amdgcn_mfma_f32_16x16x32_bf16(a, bb, av[nt], 0, 0, 0);
      }
    }
#pragma unroll
    for (int nt = 0; nt < 4; ++nt) {
      int t = nt * 16 + lr;
#pragma unroll
      for (int r = 0; r < 4; ++r) {
        int o = hb + quad * 4 + r;
        vT[o * VTS + t] = f2b(av[nt][r] + b1f[o]);
      }
    }
  }
  // ---- temporal attention (NO barrier needed: q/k in regs, vT wave-private)
  {
    // build K/Q fragments via intra-wave shuffles:
    // target elem e of frag[ms]: val[t=ms*16+lr][c=quad*8+e] (quad<2, else 0)
    // src lane = (2*quad + (e>>2))*16 + lr; register h=(e&3)>>1; half=e&1
    int s0 = ((2 * quad) & 3) * 16 + lr;
    int s1 = ((2 * quad + 1) & 3) * 16 + lr;
    v8s afs[4], bfs[4];
#pragma unroll
    for (int ms = 0; ms < 4; ++ms) {
      union { unsigned int u[4]; v8s s; } ka, qa;
      ka.u[0] = (unsigned int)__shfl((int)pkk[ms][0], s0, 64);
      ka.u[1] = (unsigned int)__shfl((int)pkk[ms][1], s0, 64);
      ka.u[2] = (unsigned int)__shfl((int)pkk[ms][0], s1, 64);
      ka.u[3] = (unsigned int)__shfl((int)pkk[ms][1], s1, 64);
      qa.u[0] = (unsigned int)__shfl((int)pkq[ms][0], s0, 64);
      qa.u[1] = (unsigned int)__shfl((int)pkq[ms][1], s0, 64);
      qa.u[2] = (unsigned int)__shfl((int)pkq[ms][0], s1, 64);
      qa.u[3] = (unsigned int)__shfl((int)pkq[ms][1], s1, 64);
      if (quad >= 2) {
        ka.u[0] = ka.u[1] = ka.u[2] = ka.u[3] = 0;
        qa.u[0] = qa.u[1] = qa.u[2] = qa.u[3] = 0;
      }
      afs[ms] = ka.s;
      bfs[ms] = qa.s;
    }
    v4f sa[4][4];
#pragma unroll
    for (int ms = 0; ms < 4; ++ms)
#pragma unroll
      for (int nt = 0; nt < 4; ++nt) sa[ms][nt] = (v4f){0.f, 0.f, 0.f, 0.f};
#pragma unroll
    for (int ms = 0; ms < 4; ++ms)
#pragma unroll
      for (int nt = 0; nt < 4; ++nt)
        sa[ms][nt] = __builtin_amdgcn_mfma_f32_16x16x32_bf16(afs[ms], bfs[nt], sa[ms][nt], 0, 0, 0);
#pragma unroll
    for (int nt = 0; nt < 4; ++nt) {
      float mx = -1e30f;
#pragma unroll
      for (int ms = 0; ms < 4; ++ms)
#pragma unroll
        for (int r = 0; r < 4; ++r) {
          float v = sa[ms][nt][r] * 0.25f;
          sa[ms][nt][r] = v;
          mx = fmaxf(mx, v);
        }
      mx = fmaxf(mx, __shfl_xor(mx, 16, 64));
      mx = fmaxf(mx, __shfl_xor(mx, 32, 64));
      float ssum = 0.f;
#pragma unroll
      for (int ms = 0; ms < 4; ++ms)
#pragma unroll
        for (int r = 0; r < 4; ++r) {
          float e = __expf(sa[ms][nt][r] - mx);
          sa[ms][nt][r] = e;
          ssum += e;
        }
      ssum += __shfl_xor(ssum, 16, 64);
      ssum += __shfl_xor(ssum, 32, 64);
      float inv = 1.f / ssum;
#pragma unroll
      for (int ms = 0; ms < 4; ++ms)
#pragma unroll
        for (int r = 0; r < 4; ++r) sa[ms][nt][r] *= inv;
    }
    v4f ov[4];
#pragma unroll
    for (int nt = 0; nt < 4; ++nt) ov[nt] = (v4f){0.f, 0.f, 0.f, 0.f};
#pragma unroll
    for (int kt = 0; kt < 2; ++kt) {
      unsigned int pA[4][2], pB[4][2];
#pragma unroll
      for (int nt = 0; nt < 4; ++nt) {
#pragma unroll
        for (int h = 0; h < 2; ++h) {
          pA[nt][h] = pk2(sa[2 * kt][nt][2 * h], sa[2 * kt][nt][2 * h + 1]);
          pB[nt][h] = pk2(sa[2 * kt + 1][nt][2 * h], sa[2 * kt + 1][nt][2 * h + 1]);
        }
      }
      v8s aV = *(const v8s*)&vT[(hb + lr) * VTS + kt * 32 + quad * 8];
#pragma unroll
      for (int nt = 0; nt < 4; ++nt) {
        union { unsigned int u[4]; v8s s; } bu;
#pragma unroll
        for (int w = 0; w < 4; ++w) {
          int src = (2 * (quad & 1) + (w >> 1)) * 16 + lr;
          unsigned int x0 = (unsigned int)__shfl((int)pA[nt][w & 1], src, 64);
          unsigned int x1 = (unsigned int)__shfl((int)pB[nt][w & 1], src, 64);
          bu.u[w] = (quad >> 1) ? x1 : x0;
        }
        ov[nt] = __builtin_amdgcn_mfma_f32_16x16x32_bf16(aV, bu.s, ov[nt], 0, 0, 0);
      }
    }
    // o -> qo (own head cols only; wave-private)
#pragma unroll
    for (int nt = 0; nt < 4; ++nt) {
      int t = nt * 16 + lr;
      *(unsigned int*)&qo[t * XBS + hb + quad * 4] = pk2(ov[nt][0], ov[nt][1]);
      *(unsigned int*)&qo[t * XBS + hb + quad * 4 + 2] = pk2(ov[nt][2], ov[nt][3]);
    }
  }
  __syncthreads();
  // ---- w2 MFMA: wave wv -> o = 16wv..+15; keep result in regs; LN partials
  v4f aw[4];
  {
#pragma unroll
    for (int nt = 0; nt < 4; ++nt) aw[nt] = (v4f){0.f, 0.f, 0.f, 0.f};
#pragma unroll
    for (int kt = 0; kt < 4; ++kt) {
      int ko = kt * 32 + quad * 8;
      v8s a = *(const v8s*)&w2B[(wv * 16 + lr) * 128 + ko];
#pragma unroll
      for (int nt = 0; nt < 4; ++nt) {
        v8s bb = *(const v8s*)&qo[(nt * 16 + lr) * XBS + ko];
        aw[nt] = __builtin_amdgcn_mfma_f32_16x16x32_bf16(a, bb, aw[nt], 0, 0, 0);
      }
    }
    int ob = hb + quad * 4;
#pragma unroll
    for (int nt = 0; nt < 4; ++nt) {
      float s = 0.f, q2 = 0.f;
#pragma unroll
      for (int r = 0; r < 4; ++r) {
        aw[nt][r] += b2f[ob + r];
        s += aw[nt][r];
        q2 += aw[nt][r] * aw[nt][r];
      }
      s += __shfl_xor(s, 16, 64);  s += __shfl_xor(s, 32, 64);
      q2 += __shfl_xor(q2, 16, 64); q2 += __shfl_xor(q2, 32, 64);
      if (quad == 0) {
        pS[wv * 64 + nt * 16 + lr] = s;
        pQ[wv * 64 + nt * 16 + lr] = q2;
      }
    }
  }
  __syncthreads();
  if (tid < 64) {
    float s = 0.f, q2 = 0.f;
#pragma unroll
    for (int w = 0; w < 8; ++w) { s += pS[w * 64 + tid]; q2 += pQ[w * 64 + tid]; }
    float mm = s * (1.f / 128.f);
    mrow[tid] = mm;
    vrow[tid] = rsqrtf(q2 * (1.f / 128.f) - mm * mm + 1e-5f);
  }
  __syncthreads();
  // ---- LN0 + residual -> g0
  {
    int ob = hb + quad * 4;
    float gg[4], bb2[4];
#pragma unroll
    for (int r = 0; r < 4; ++r) { gg[r] = l0g[ob + r]; bb2[r] = l0b[ob + r]; }
    float* dst = g0 + (size_t)bn * TILE;
#pragma unroll
    for (int nt = 0; nt < 4; ++nt) {
      int t = nt * 16 + lr;
      float m = mrow[t], rs = vrow[t];
      ushort4 xr = *(const ushort4*)&Xb[(t + 1) * XBS + ob];
      float4 o4;
      o4.x = (aw[nt][0] - m) * rs * gg[0] + bb2[0] + bfu(xr.x);
      o4.y = (aw[nt][1] - m) * rs * gg[1] + bb2[1] + bfu(xr.y);
      o4.z = (aw[nt][2] - m) * rs * gg[2] + bb2[2] + bfu(xr.z);
      o4.w = (aw[nt][3] - m) * rs * gg[3] + bb2[3] + bfu(xr.w);
      *(float4*)&dst[t * 128 + ob] = o4;
    }
  }
}

// ================================================================ megasp v7 — wave-local LN1. (unchanged)
constexpr int XS = 136;   // R1/R2 row stride (ushort): 272B, 16B-aligned
constexpr int TS = 264;   // Xt row stride (ushort): 528B, 16B-aligned

__global__ __launch_bounds__(512, 1) void k_megasp(
    const float* g0, const float* lap, const unsigned short* thB,
    const float* l1g, const float* l1b, const float* e, unsigned short* g0b) {
  int bt = blockIdx.x, b = bt >> 6, t = bt & 63;
  __shared__ unsigned short R1[256 * XS];   // Xhi -> P -> theta[128][136]
  __shared__ unsigned short R2[256 * XS];   // Xlo -> Xt[128][TS] -> yB[256][136]
  unsigned short* Xhi = R1;
  unsigned short* Xlo = R2;
  unsigned short* Xt = R2;
  unsigned short* Pld = R1;
  int tid = threadIdx.x;
  int wv = tid >> 6, lane = tid & 63, quad = lane >> 4, lr = lane & 15;
  int wrow0 = wv * 32;
  const float sc = 0.08838834764831845f;
  // ---- stage x(b,t): g0 rows -> bf16 hi/lo split
  {
    size_t base = (size_t)b * (N * (size_t)TILE) + (size_t)t * 128;
    for (int idx = tid * 4; idx < 32768; idx += 2048) {
      int n = idx >> 7, c = idx & 127;
      float4 v4 = *(const float4*)&g0[base + (size_t)n * TILE + c];
      ushort4 h, l;
      h.x = f2b(v4.x); l.x = f2b(v4.x - bfu(h.x));
      h.y = f2b(v4.y); l.y = f2b(v4.y - bfu(h.y));
      h.z = f2b(v4.z); l.z = f2b(v4.z - bfu(h.z));
      h.w = f2b(v4.w); l.w = f2b(v4.w - bfu(h.w));
      *(ushort4*)&Xhi[n * XS + c] = h;
      *(ushort4*)&Xlo[n * XS + c] = l;
    }
  }
  __syncthreads();
  // ---- QK: wave wv -> S rows [32wv, 32wv+32), all 256 cols, K=128
  v4f acc[2][16];
#pragma unroll
  for (int mi = 0; mi < 2; ++mi)
#pragma unroll
    for (int nt = 0; nt < 16; ++nt) acc[mi][nt] = (v4f){0.f, 0.f, 0.f, 0.f};
  for (int kt = 0; kt < 4; ++kt) {
    int ko = kt * 32 + quad * 8;
    v8s ah0 = *(const v8s*)&Xhi[(wrow0 + lr) * XS + ko];
    v8s al0 = *(const v8s*)&Xlo[(wrow0 + lr) * XS + ko];
    v8s ah1 = *(const v8s*)&Xhi[(wrow0 + 16 + lr) * XS + ko];
    v8s al1 = *(const v8s*)&Xlo[(wrow0 + 16 + lr) * XS + ko];
#pragma unroll
    for (int nt = 0; nt < 16; ++nt) {
      v8s bh = *(const v8s*)&Xhi[(nt * 16 + lr) * XS + ko];
      v8s bl = *(const v8s*)&Xlo[(nt * 16 + lr) * XS + ko];
      acc[0][nt] = __builtin_amdgcn_mfma_f32_16x16x32_bf16(ah0, bh, acc[0][nt], 0, 0, 0);
      acc[0][nt] = __builtin_amdgcn_mfma_f32_16x16x32_bf16(ah0, bl, acc[0][nt], 0, 0, 0);
      acc[0][nt] = __builtin_amdgcn_mfma_f32_16x16x32_bf16(al0, bh, acc[0][nt], 0, 0, 0);
      acc[1][nt] = __builtin_amdgcn_mfma_f32_16x16x32_bf16(ah1, bh, acc[1][nt], 0, 0, 0);
      acc[1][nt] = __builtin_amdgcn_mfma_f32_16x16x32_bf16(ah1, bl, acc[1][nt], 0, 0, 0);
      acc[1][nt] = __builtin_amdgcn_mfma_f32_16x16x32_bf16(al1, bh, acc[1][nt], 0, 0, 0);
    }
  }
  __syncthreads();
  // ---- build Xt[c][n] = Xhi[n][c] (overwrites Xlo)
  for (int task = tid; task < 8192; task += 512) {
    int c = task & 127, n0 = (task >> 7) * 4;
    ushort4 w;
    w.x = Xhi[(n0 + 0) * XS + c];
    w.y = Xhi[(n0 + 1) * XS + c];
    w.z = Xhi[(n0 + 2) * XS + c];
    w.w = Xhi[(n0 + 3) * XS + c];
    *(ushort4*)&Xt[c * TS + n0] = w;
  }
  __syncthreads();
  // ---- softmax + Lap scale; write P half0 (cols 0..127); pack half1 in regs.
  unsigned int pk1[2][8][2];
#pragma unroll
  for (int mi = 0; mi < 2; ++mi) {
#pragma unroll
    for (int r = 0; r < 4; ++r) {
      int row = wrow0 + 16 * mi + quad * 4 + r;
      float mx = -1e30f;
#pragma unroll
      for (int nt = 0; nt < 16; ++nt) {
        acc[mi][nt][r] *= sc;
        mx = fmaxf(mx, acc[mi][nt][r]);
      }
#pragma unroll
      for (int m = 8; m > 0; m >>= 1) mx = fmaxf(mx, __shfl_xor(mx, m, 16));
      float ex[16];
      float ssum = 0.f;
#pragma unroll
      for (int nt = 0; nt < 16; ++nt) { ex[nt] = __expf(acc[mi][nt][r] - mx); ssum += ex[nt]; }
#pragma unroll
      for (int m = 8; m > 0; m >>= 1) ssum += __shfl_xor(ssum, m, 16);
      float inv = sc / ssum;
      const float* lrow = lap + row * 256 + lr;
#pragma unroll
      for (int nt = 0; nt < 8; ++nt)
        Pld[row * XS + nt * 16 + lr] = f2b(ex[nt] * inv * lrow[nt * 16]);
#pragma unroll
      for (int nt = 8; nt < 16; ++nt) {
        unsigned int hbw = (unsigned int)f2b(ex[nt] * inv * lrow[nt * 16]);
        if ((r & 1) == 0) pk1[mi][nt - 8][r >> 1] = hbw;
        else pk1[mi][nt - 8][r >> 1] |= hbw << 16;
      }
    }
  }
  // ---- PV: y[n][c] = sum_m P[n][m] * Xt[c][m]; two K-halves of 128.
  v4f acc2[2][8];
#pragma unroll
  for (int mi = 0; mi < 2; ++mi)
#pragma unroll
    for (int nt = 0; nt < 8; ++nt) acc2[mi][nt] = (v4f){0.f, 0.f, 0.f, 0.f};
#pragma unroll
  for (int h = 0; h < 2; ++h) {
    if (h == 1) {
#pragma unroll
      for (int mi = 0; mi < 2; ++mi) {
        int rowb = wrow0 + 16 * mi + quad * 4;
#pragma unroll
        for (int k = 0; k < 8; ++k) {
          int col = k * 16 + lr;
          unsigned int u0 = pk1[mi][k][0], u1 = pk1[mi][k][1];
          Pld[(rowb + 0) * XS + col] = (unsigned short)u0;
          Pld[(rowb + 1) * XS + col] = (unsigned short)(u0 >> 16);
          Pld[(rowb + 2) * XS + col] = (unsigned short)u1;
          Pld[(rowb + 3) * XS + col] = (unsigned short)(u1 >> 16);
        }
      }
    }
    for (int kt = 0; kt < 4; ++kt) {
      int ko = kt * 32 + quad * 8;
      v8s pa0 = *(const v8s*)&Pld[(wrow0 + lr) * XS + ko];
      v8s pa1 = *(const v8s*)&Pld[(wrow0 + 16 + lr) * XS + ko];
#pragma unroll
      for (int nt = 0; nt < 8; ++nt) {
        v8s xb = *(const v8s*)&Xt[(nt * 16 + lr) * TS + h * 128 + ko];
        acc2[0][nt] = __builtin_amdgcn_mfma_f32_16x16x32_bf16(pa0, xb, acc2[0][nt], 0, 0, 0);
        acc2[1][nt] = __builtin_amdgcn_mfma_f32_16x16x32_bf16(pa1, xb, acc2[1][nt], 0, 0, 0);
      }
    }
  }
  __syncthreads();
  // ---- y -> bf16 yB (over Xt region, own rows); stage theta (over P region)
  unsigned short* yB = R2;
  unsigned short* ths = R1;
#pragma unroll
  for (int mi = 0; mi < 2; ++mi) {
    int nb = wrow0 + 16 * mi + quad * 4;
#pragma unroll
    for (int nt = 0; nt < 8; ++nt) {
      int c = nt * 16 + lr;
#pragma unroll
      for (int r = 0; r < 4; ++r)
        yB[(nb + r) * XS + c] = f2b(acc2[mi][nt][r]);
    }
  }
  for (int idx = tid * 8; idx < 16384; idx += 4096) {
    int o = idx >> 7, k = idx & 127;
    *(uint4*)&ths[o * 136 + k] = *(const uint4*)&thB[idx];
  }
  __syncthreads();
  // ---- theta GEMM (n-partitioned): wave wv -> n-tiles {2wv, 2wv+1}, all 8 o-tiles
  v4f acc3[2][8];
#pragma unroll
  for (int nt2 = 0; nt2 < 2; ++nt2)
#pragma unroll
    for (int ot = 0; ot < 8; ++ot) acc3[nt2][ot] = (v4f){0.f, 0.f, 0.f, 0.f};
#pragma unroll
  for (int kt = 0; kt < 4; ++kt) {
    int ko = kt * 32 + quad * 8;
    v8s b0 = *(const v8s*)&yB[((wv * 2 + 0) * 16 + lr) * XS + ko];
    v8s b1 = *(const v8s*)&yB[((wv * 2 + 1) * 16 + lr) * XS + ko];
#pragma unroll
    for (int ot = 0; ot < 8; ++ot) {
      v8s a = *(const v8s*)&ths[(ot * 16 + lr) * 136 + ko];
      acc3[0][ot] = __builtin_amdgcn_mfma_f32_16x16x32_bf16(a, b0, acc3[0][ot], 0, 0, 0);
      acc3[1][ot] = __builtin_amdgcn_mfma_f32_16x16x32_bf16(a, b1, acc3[1][ot], 0, 0, 0);
    }
  }
  // ---- relu + wave-local LN1
  float mmv[2], rrv[2];
#pragma unroll
  for (int nt2 = 0; nt2 < 2; ++nt2) {
    float s = 0.f, q2 = 0.f;
#pragma unroll
    for (int ot = 0; ot < 8; ++ot)
#pragma unroll
      for (int r = 0; r < 4; ++r) {
        float v = fmaxf(acc3[nt2][ot][r], 0.f);
        acc3[nt2][ot][r] = v;
        s += v; q2 += v * v;
      }
    s += __shfl_xor(s, 16, 64);  s += __shfl_xor(s, 32, 64);
    q2 += __shfl_xor(q2, 16, 64); q2 += __shfl_xor(q2, 32, 64);
    mmv[nt2] = s * (1.f / 128.f);
    rrv[nt2] = rsqrtf(q2 * (1.f / 128.f) - mmv[nt2] * mmv[nt2] + 1e-5f);
  }
  // ---- LN1 + residual + e -> g0b (bf16)
  {
    const float* eb = e + b * 128;
#pragma unroll
    for (int ot = 0; ot < 8; ++ot) {
      int o0 = ot * 16 + quad * 4;
      float gg[4], bb2[4], ev[4];
#pragma unroll
      for (int r = 0; r < 4; ++r) { gg[r] = l1g[o0 + r]; bb2[r] = l1b[o0 + r]; ev[r] = eb[o0 + r]; }
#pragma unroll
      for (int nt2 = 0; nt2 < 2; ++nt2) {
        int n = (wv * 2 + nt2) * 16 + lr;
        float m = mmv[nt2], rs = rrv[nt2];
        size_t ga = ((size_t)(b * 256 + n)) * TILE + (size_t)t * 128 + o0;
        float4 xa = *(const float4*)&g0[ga];
        ushort4 pk;
        pk.x = f2b((acc3[nt2][ot][0] - m) * rs * gg[0] + bb2[0] + xa.x + ev[0]);
        pk.y = f2b((acc3[nt2][ot][1] - m) * rs * gg[1] + bb2[1] + xa.y + ev[1]);
        pk.z = f2b((acc3[nt2][ot][2] - m) * rs * gg[2] + bb2[2] + xa.z + ev[2]);
        pk.w = f2b((acc3[nt2][ot][3] - m) * rs * gg[3] + bb2[3] + xa.w + ev[3]);
        *(ushort4*)&g0b[ga] = pk;
      }
    }
  }
}

// ================================================================ megadec v6 — dxc hoisted into phase A.
__global__ __launch_bounds__(512, 4) void k_megadec(
    const unsigned short* g0b, const unsigned short* decW, const float* decb,
    const unsigned short* dxcW, const float* dxcb,
    const unsigned short* dc1W, const float* dc1b,
    const float* dp2w, const float* dp2b, const int* flag, void* outv) {
  int bn = blockIdx.x, b = bn >> 8, n = bn & 255;
  int f32o = flag[0];
  __shared__ unsigned short Xm[66 * XBS];   // enc bf16, row t+1; rows 0,65 zero
  __shared__ unsigned short E2[66 * XBS];   // ec  bf16, row t+1; rows 0,65 zero
  __shared__ float pb0[8][64], pb1[8][64];
  int tid = threadIdx.x;
  int wv = tid >> 6, lane = tid & 63, quad = lane >> 4, lr = lane & 15;
  int m0 = wv * 16;
  const unsigned short* gp = g0b + (size_t)bn * TILE;
  for (int idx = tid * 8; idx < TILE; idx += 4096) {
    int t = idx >> 7, c = idx & 127;
    *(uint4*)&Xm[(t + 1) * XBS + c] = *(const uint4*)&gp[idx];
  }
  if (tid < 128) {
    Xm[tid] = 0; Xm[65 * XBS + tid] = 0;
    E2[tid] = 0; E2[65 * XBS + tid] = 0;
  }
  __syncthreads();
  // ---- phase A: dec conv + dxc conv (both over Xm, 3-shift)
  v4f acc[4], ax[4];
  float ecv[4][4];
#pragma unroll
  for (int nt = 0; nt < 4; ++nt) { acc[nt] = (v4f){0.f,0.f,0.f,0.f}; ax[nt] = (v4f){0.f,0.f,0.f,0.f}; }
  for (int j = 0; j < 3; ++j) {
#pragma unroll
    for (int kt = 0; kt < 4; ++kt) {
      int wo = (m0 + lr) * 384 + j * 128 + kt * 32 + quad * 8;
      v8s aD = *(const v8s*)&decW[wo];
      v8s aX = *(const v8s*)&dxcW[wo];
      int bko = kt * 32 + quad * 8;
#pragma unroll
      for (int nt = 0; nt < 4; ++nt) {
        v8s bb = *(const v8s*)&Xm[(nt * 16 + lr + j) * XBS + bko];
        acc[nt] = __builtin_amdgcn_mfma_f32_16x16x32_bf16(aD, bb, acc[nt], 0, 0, 0);
        ax[nt]  = __builtin_amdgcn_mfma_f32_16x16x32_bf16(aX, bb, ax[nt], 0, 0, 0);
      }
    }
  }
#pragma unroll
  for (int nt = 0; nt < 4; ++nt) {
    int t = nt * 16 + lr;
    int o = m0 + quad * 4;
    ushort4 pk;
#pragma unroll
    for (int r = 0; r < 4; ++r) {
      float v = acc[nt][r] + decb[o + r];
      ecv[nt][r] = v;
      ((unsigned short*)&pk)[r] = f2b(v);
    }
    *(ushort4*)&E2[(t + 1) * XBS + o] = pk;
  }
  __syncthreads();
  // ---- phase B: dc1 conv over E2 (3-shift)
  v4f ac[4];
#pragma unroll
  for (int nt = 0; nt < 4; ++nt) ac[nt] = (v4f){0.f, 0.f, 0.f, 0.f};
  for (int j = 0; j < 3; ++j) {
#pragma unroll
    for (int kt = 0; kt < 4; ++kt) {
      v8s a2 = *(const v8s*)&dc1W[(m0 + lr) * 384 + j * 128 + kt * 32 + quad * 8];
      int bko = kt * 32 + quad * 8;
#pragma unroll
      for (int nt = 0; nt < 4; ++nt) {
        v8s b2v = *(const v8s*)&E2[(nt * 16 + lr + j) * XBS + bko];
        ac[nt] = __builtin_amdgcn_mfma_f32_16x16x32_bf16(a2, b2v, ac[nt], 0, 0, 0);
      }
    }
  }
#pragma unroll
  for (int nt = 0; nt < 4; ++nt) {
    float p0 = 0.f, p1 = 0.f;
#pragma unroll
    for (int r = 0; r < 4; ++r) {
      int o = m0 + quad * 4 + r;
      float v = fmaxf(ax[nt][r] + dxcb[o] + sigm(ecv[nt][r]) + ac[nt][r] + dc1b[o], 0.f);
      p0 += v * dp2w[o];
      p1 += v * dp2w[128 + o];
    }
    p0 += __shfl_xor(p0, 16, 64); p0 += __shfl_xor(p0, 32, 64);
    p1 += __shfl_xor(p1, 16, 64); p1 += __shfl_xor(p1, 32, 64);
    if (quad == 0) { pb0[wv][nt * 16 + lr] = p0; pb1[wv][nt * 16 + lr] = p1; }
  }
  __syncthreads();
  if (tid < 128) {
    int ch = tid >> 6, t = tid & 63;
    float s = 0.f;
    if (ch == 0) { for (int w = 0; w < 8; ++w) s += pb0[w][t]; s += dp2b[0]; }
    else         { for (int w = 0; w < 8; ++w) s += pb1[w][t]; s += dp2b[1]; }
    size_t oi = ((size_t)(b * 2 + ch) * 256 + n) * 64 + t;
    if (f32o) ((float*)outv)[oi] = s;
    else ((__hip_bfloat16*)outv)[oi] = __float2bfloat16(s);
  }
}

}  // namespace

extern "C" void kernel_launch(void* const* d_in, const int* in_sizes, int n_in,
                              void* d_out, int out_size, void* d_ws, size_t ws_size,
                              hipStream_t stream) {
  (void)in_sizes; (void)n_in; (void)out_size; (void)ws_size;
  const void* x    = d_in[0];
  const void* adj  = d_in[1];
  const int*  step = (const int*)d_in[2];
  const void* wq   = d_in[3];
  const void* bq   = d_in[4];
  const void* wk   = d_in[5];
  const void* bk   = d_in[6];
  const void* w1   = d_in[7];
  const void* b1   = d_in[8];
  const void* w2   = d_in[9];
  const void* b2   = d_in[10];
  const void* th   = d_in[11];
  const void* l0g  = d_in[12];
  const void* l0b  = d_in[13];
  const void* l1g  = d_in[14];
  const void* l1b  = d_in[15];
  const void* p1w  = d_in[16];
  const void* p1b  = d_in[17];
  const void* p2w  = d_in[18];
  const void* p2b  = d_in[19];
  const void* dxcw = d_in[20];
  const void* dxcb = d_in[21];
  const void* decw = d_in[22];
  const void* decb = d_in[23];
  const void* dc1w = d_in[24];
  const void* dc1b = d_in[25];
  const void* dp2w = d_in[26];
  const void* dp2b = d_in[27];

  float* ws = (float*)d_ws;
  int* flag = (int*)ws;
  float* p = ws + 16;
  float* e     = p; p += 1024;
  float* lap   = p; p += 65536;
  float* dshv  = p; p += 256;
  float* wqkBv = p; p += 49152;   // 98304 bf16
  float* w1Bv  = p; p += 8192;    // 16384 bf16
  float* w2Bv  = p; p += 8192;
  float* thBv  = p; p += 8192;
  float* decWv = p; p += 24576;   // 49152 bf16
  float* dxcWv = p; p += 24576;
  float* dc1Wv = p; p += 24576;
  float* bqk   = p; p += 256;
  float* b1f   = p; p += 128;
  float* b2f   = p; p += 128;
  float* l0gf  = p; p += 128;
  float* l0bf  = p; p += 128;
  float* l1gf  = p; p += 128;
  float* l1bf  = p; p += 128;
  float* dxcbf = p; p += 128;
  float* decbf = p; p += 128;
  float* dc1bf = p; p += 128;
  float* dp2wf = p; p += 256;
  float* dp2bf = p; p += 8;
  size_t off = (size_t)(p - ws);
  off = (off + 127) & ~(size_t)127;
  float* xf = ws + off;            // BIGE scratch: g0b (bf16 xp') lives here
  float* g0 = xf + BIGE;           // BIGE floats (67 MB)
  unsigned short* g0b = (unsigned short*)xf;

  PrepArgs pa;
  pa.flag = flag;
  pa.wq = wq; pa.wk = wk; pa.w1 = w1; pa.w2 = w2; pa.th = th;
  pa.dxc = dxcw; pa.dec = decw; pa.dc1 = dc1w;
  pa.bq = bq; pa.bk = bk; pa.b1 = b1; pa.b2 = b2;
  pa.l0g = l0g; pa.l0b = l0b; pa.l1g = l1g; pa.l1b = l1b;
  pa.dxcb = dxcb; pa.decb = decb; pa.dc1b = dc1b; pa.dp2w = dp2w; pa.dp2b = dp2b;
  pa.wqkB = (unsigned short*)wqkBv;
  pa.w1B = (unsigned short*)w1Bv;
  pa.w2B = (unsigned short*)w2Bv;
  pa.thB = (__hip_bfloat16*)thBv;
  pa.decWb = (unsigned short*)decWv;
  pa.dxcWb = (unsigned short*)dxcWv;
  pa.dc1Wb = (unsigned short*)dc1Wv;
  pa.bqk = bqk; pa.b1f = b1f; pa.b2f = b2f;
  pa.l0gf = l0gf; pa.l0bf = l0bf; pa.l1gf = l1gf; pa.l1bf = l1bf;
  pa.dxcbf = dxcbf; pa.decbf = decbf; pa.dc1bf = dc1bf; pa.dp2wf = dp2wf; pa.dp2bf = dp2bf;

  k_sniff<<<1, 64, 0, stream>>>((const unsigned short*)x, flag);
  k_dsh<<<32, 256, 0, stream>>>(adj, flag, dshv);
  k_prepall<<<200, 256, 0, stream>>>(pa, adj, dshv, lap, step, p1w, p1b, p2w, p2b, e);

  k_mega1<<<2048, 512, 0, stream>>>(x, flag, (const unsigned short*)wqkBv, bqk,
                                    (const unsigned short*)w1Bv, b1f,
                                    (const unsigned short*)w2Bv, b2f, l0gf, l0bf, g0);
  k_megasp<<<512, 512, 0, stream>>>(g0, lap, (const unsigned short*)thBv,
                                    l1gf, l1bf, e, g0b);
  k_megadec<<<2048, 512, 0, stream>>>(g0b, (const unsigned short*)decWv, decbf,
                                      (const unsigned short*)dxcWv, dxcbf,
                                      (const unsigned short*)dc1Wv, dc1bf,
                                      dp2wf, dp2bf, flag, d_out);
}